// Round 1
// baseline (344.590 us; speedup 1.0000x reference)
//
#include <hip/hip_runtime.h>
#include <hip/hip_fp16.h>

#define ND 64
#define BG 256        // dst ids per bucket
#define MAXB 512      // max buckets (LDS sizing); nb = ceil(2N/BG) = 391
#define PCH 16384     // edges per partition chunk: 196 part-blocks
#define CAP 9216      // per-bucket slab capacity; lambda=8184, sigma~90 -> 11-sigma margin

__device__ __forceinline__ float lrelu(float x) { return x > 0.f ? x : 0.2f * x; }

__device__ __forceinline__ float wave_sum(float v) {
#pragma unroll
    for (int m = 32; m > 0; m >>= 1) v += __shfl_xor(v, m, 64);
    return v;
}

// 8 fp16 x fp32 fused into 8 fp32 accumulators — scalar form so the compiler
// can emit v_fma_mix_f32 (fp16 source converted in the FMA, no separate cvt)
__device__ __forceinline__ void fma8(float* acc, float w, int4 raw) {
    union { int4 i; __half h[8]; } u;
    u.i = raw;
#pragma unroll
    for (int i = 0; i < 8; i++) acc[i] = fmaf(w, __half2float(u.h[i]), acc[i]);
}

// ---------------- bucketed CSR build (fixed-capacity slabs) ----------------
// combined dst index idx = graph*N + dst in [0, n2); bucket = idx >> 8.
// Bucket b owns part[b*CAP .. b*CAP+cnt) and csr[b*CAP .. b*CAP+cnt).

__global__ void init_cursor(int* __restrict__ bcursor, int nb) {
    int t = threadIdx.x;
    if (t < nb) bcursor[t] = t * CAP;
}

// ---- partition body: multi-split into reserved runs; entry (src<<8 | idx&255) ----
// Fast path (full chunk): 16 edges/thread stashed in registers across passes —
// pass 2 does zero global loads.
__device__ void partition_body(int* hist, int* lcur,
                               const int* __restrict__ eI, const int* __restrict__ eP,
                               int* __restrict__ bcursor, int* __restrict__ part,
                               int N, int E, int nb) {
    int t = threadIdx.x;
    int total = 2 * E;
    int chunkBase = blockIdx.x * PCH;
    int cnt = min(PCH, total - chunkBase);
    if (t < nb) hist[t] = 0;
    __syncthreads();

    if (cnt == PCH) {
        int pk[16];
        unsigned bkp[8];
#pragma unroll
        for (int it = 0; it < 4; it++) {
            int i = t * 4 + it * 4096;
            int e = chunkBase + i;
            int sv[4], dv[4];
            if (e + 3 < E) {
                int4 a = *(const int4*)(eI + e);
                int4 b = *(const int4*)(eI + E + e);
                sv[0] = a.x; sv[1] = a.y; sv[2] = a.z; sv[3] = a.w;
                dv[0] = b.x; dv[1] = b.y; dv[2] = b.z; dv[3] = b.w;
            } else if (e >= E) {
                int4 a = *(const int4*)(eP + (e - E));
                int4 b = *(const int4*)(eP + E + (e - E));
                sv[0] = a.x; sv[1] = a.y; sv[2] = a.z; sv[3] = a.w;
                dv[0] = b.x + N; dv[1] = b.y + N; dv[2] = b.z + N; dv[3] = b.w + N;
            } else {
#pragma unroll
                for (int k = 0; k < 4; k++) {
                    int ee = e + k;
                    if (ee < E) { sv[k] = eI[ee]; dv[k] = eI[E + ee]; }
                    else        { sv[k] = eP[ee - E]; dv[k] = N + eP[E + ee - E]; }
                }
            }
#pragma unroll
            for (int k = 0; k < 4; k++) {
                int j = it * 4 + k;
                int bk = dv[k] >> 8;
                pk[j] = (sv[k] << 8) | (dv[k] & 255);
                atomicAdd(&hist[bk], 1);
                if ((j & 1) == 0) bkp[j >> 1] = (unsigned)bk;
                else bkp[j >> 1] |= (unsigned)bk << 16;
            }
        }
        __syncthreads();
        if (t < nb) lcur[t] = hist[t] ? atomicAdd(&bcursor[t], hist[t]) : 0;
        __syncthreads();
#pragma unroll
        for (int j = 0; j < 16; j++) {
            int bk = (bkp[j >> 1] >> ((j & 1) * 16)) & 0xffff;
            int pos = atomicAdd(&lcur[bk], 1);
            part[pos] = pk[j];
        }
        return;
    }

    // slow path (tail chunk only)
    int cnt4 = cnt & ~3;
    for (int i = t * 4; i < cnt4; i += 4096) {
        int e = chunkBase + i;
        int4 d; int base;
        if (e + 3 < E)   { d = *(const int4*)(eI + E + e); base = 0; }
        else if (e >= E) { d = *(const int4*)(eP + E + (e - E)); base = N; }
        else {
            int tmp[4];
#pragma unroll
            for (int k = 0; k < 4; k++) {
                int ee = e + k;
                tmp[k] = (ee < E) ? eI[E + ee] : N + eP[E + ee - E];
            }
            d = make_int4(tmp[0], tmp[1], tmp[2], tmp[3]); base = 0;
        }
        atomicAdd(&hist[(base + d.x) >> 8], 1);
        atomicAdd(&hist[(base + d.y) >> 8], 1);
        atomicAdd(&hist[(base + d.z) >> 8], 1);
        atomicAdd(&hist[(base + d.w) >> 8], 1);
    }
    for (int i = cnt4 + t; i < cnt; i += 1024) {
        int e = chunkBase + i;
        int idx = (e < E) ? eI[E + e] : N + eP[E + (e - E)];
        atomicAdd(&hist[idx >> 8], 1);
    }
    __syncthreads();
    if (t < nb) lcur[t] = hist[t] ? atomicAdd(&bcursor[t], hist[t]) : 0;
    __syncthreads();
    for (int i = t; i < cnt; i += 1024) {
        int e = chunkBase + i;
        int s, idx;
        if (e < E) { s = eI[e]; idx = eI[E + e]; }
        else       { s = eP[e - E]; idx = N + eP[E + (e - E)]; }
        int pos = atomicAdd(&lcur[idx >> 8], 1);
        part[pos] = (s << 8) | (idx & 255);
    }
}

// ---- gemm body: h(fp16) = x @ W + score dots; 16 waves/block, 4 nodes/wave ----
__device__ void gemm_body(float* xsAll, int gb,
                          const float* __restrict__ xA, const float* __restrict__ xB,
                          const float* __restrict__ WA, const float* __restrict__ WB,
                          const float* __restrict__ asA, const float* __restrict__ adA,
                          const float* __restrict__ asB, const float* __restrict__ adB,
                          __half* __restrict__ h16, float* __restrict__ ssrc,
                          float* __restrict__ sdst, int N) {
    int half = gb & 1;
    int blk = gb >> 1;
    int wave = threadIdx.x >> 6;
    int lane = threadIdx.x & 63;
    const float* x  = half ? xB : xA;
    const float* W  = half ? WB : WA;
    const float* av_ = half ? asB : asA;
    const float* dv_ = half ? adB : adA;
    int nodeBase = (blk * 16 + wave) * 4;      // within half
    float* xs = xsAll + wave * (4 * ND);

    if (nodeBase + 3 < N) {
        *(float4*)&xs[lane * 4] = *(const float4*)&x[(size_t)nodeBase * ND + lane * 4];
    } else if (nodeBase < N) {
#pragma unroll
        for (int i = 0; i < 4; i++) {
            int gi = nodeBase * ND + lane * 4 + i;
            xs[lane * 4 + i] = (gi < N * ND) ? x[gi] : 0.f;
        }
    }
    __syncthreads();
    if (nodeBase >= N) return;

    float4 acc = {0.f, 0.f, 0.f, 0.f};
#pragma unroll
    for (int k = 0; k < ND; k++) {
        float wv = W[k * ND + lane];
        acc.x = fmaf(xs[0 * ND + k], wv, acc.x);
        acc.y = fmaf(xs[1 * ND + k], wv, acc.y);
        acc.z = fmaf(xs[2 * ND + k], wv, acc.z);
        acc.w = fmaf(xs[3 * ND + k], wv, acc.w);
    }
    float av = av_[lane], dv = dv_[lane];
    float s1x = wave_sum(acc.x * av), s2x = wave_sum(acc.x * dv);
    float s1y = wave_sum(acc.y * av), s2y = wave_sum(acc.y * dv);
    float s1z = wave_sum(acc.z * av), s2z = wave_sum(acc.z * dv);
    float s1w = wave_sum(acc.w * av), s2w = wave_sum(acc.w * dv);

    int g0 = half * N + nodeBase;
    h16[(size_t)(g0 + 0) * ND + lane] = __float2half(acc.x);
    if (nodeBase + 1 < N) h16[(size_t)(g0 + 1) * ND + lane] = __float2half(acc.y);
    if (nodeBase + 2 < N) h16[(size_t)(g0 + 2) * ND + lane] = __float2half(acc.z);
    if (nodeBase + 3 < N) h16[(size_t)(g0 + 3) * ND + lane] = __float2half(acc.w);
    if (lane == 0) {
        ssrc[g0] = s1x; sdst[g0] = s2x;
        if (nodeBase + 1 < N) { ssrc[g0 + 1] = s1y; sdst[g0 + 1] = s2y; }
        if (nodeBase + 2 < N) { ssrc[g0 + 2] = s1z; sdst[g0 + 2] = s2z; }
        if (nodeBase + 3 < N) { ssrc[g0 + 3] = s1w; sdst[g0 + 3] = s2w; }
    }
}

// ---- fused: partition (blocks < partBlocks) | layer-1 gemm (the rest) ----
__global__ void __launch_bounds__(1024) part_gemm(
        const int* __restrict__ eI, const int* __restrict__ eP,
        int* __restrict__ bcursor, int* __restrict__ part,
        const float* __restrict__ xA, const float* __restrict__ xB,
        const float* __restrict__ WA, const float* __restrict__ WB,
        const float* __restrict__ asA, const float* __restrict__ adA,
        const float* __restrict__ asB, const float* __restrict__ adB,
        __half* __restrict__ h16, float* __restrict__ ssrc, float* __restrict__ sdst,
        int N, int E, int nb, int partBlocks) {
    __shared__ int smem[16 * 4 * ND];   // 16 KB: part uses 4 KB (hist+lcur); gemm uses all
    if (blockIdx.x < partBlocks) {
        partition_body(smem, smem + MAXB, eI, eP, bcursor, part, N, E, nb);
    } else {
        gemm_body((float*)smem, blockIdx.x - partBlocks,
                  xA, xB, WA, WB, asA, adA, asB, adB, h16, ssrc, sdst, N);
    }
}

// one block (1024 thr) per bucket: per-(dst,src-quartile) hist + scan -> row/deg,
// LDS-slab scatter + per-key insertion sort by src id (quartile is monotone in
// src, so rows come out fully src-sorted => csr is BIT-DETERMINISTIC regardless
// of atomic scatter order), then coalesced copy-out.
__global__ void bucket_build(const int* __restrict__ part, const int* __restrict__ bcursor,
                             int* __restrict__ row, int* __restrict__ deg,
                             int* __restrict__ csr, int n2, int N) {
    __shared__ int lhist[BG * 4];     // 1024 keys: dstLow*4 + srcQuartile
    __shared__ int lrow[BG * 4];
    __shared__ int slab[CAP];         // 36 KB staging for deterministic sort
    int b = blockIdx.x, t = threadIdx.x;   // blockDim == 1024
    int start = b * CAP;
    int cnt = min(bcursor[b] - start, CAP);
    int cnt4 = cnt & ~3;
    int q1 = N >> 2, q2 = N >> 1, q3 = q1 + q2;
    auto key = [&](int p) {
        int s = p >> 8;
        int q = (s >= q2) ? 2 : 0;
        q += (s >= (q ? q3 : q1)) ? 1 : 0;
        return ((p & 255) << 2) | q;
    };
    lhist[t] = 0;
    __syncthreads();
    for (int j = t * 4; j < cnt4; j += 4096) {
        int4 p = *(const int4*)(part + start + j);
        atomicAdd(&lhist[key(p.x)], 1);
        atomicAdd(&lhist[key(p.y)], 1);
        atomicAdd(&lhist[key(p.z)], 1);
        atomicAdd(&lhist[key(p.w)], 1);
    }
    for (int j = cnt4 + t; j < cnt; j += 1024) atomicAdd(&lhist[key(part[start + j])], 1);
    __syncthreads();
    int v = lhist[t];
    lrow[t] = v;
    __syncthreads();
    for (int off = 1; off < 1024; off <<= 1) {
        int a = (t >= off) ? lrow[t - off] : 0;
        __syncthreads();
        lrow[t] += a;
        __syncthreads();
    }
    // lrow = inclusive scan; key t's slab-relative segment = [lrow[t]-v, lrow[t])
    if (t < BG) {
        int g = b * BG + t;
        if (g < n2) {
            row[g] = start + lrow[4 * t] - lhist[4 * t];
            deg[g] = lhist[4 * t] + lhist[4 * t + 1] + lhist[4 * t + 2] + lhist[4 * t + 3];
        }
    }
    __syncthreads();
    lhist[t] = lrow[t] - v;           // reuse as LDS-relative write cursor
    __syncthreads();
    for (int j = t * 4; j < cnt4; j += 4096) {
        int4 p = *(const int4*)(part + start + j);
        int pos;
        pos = atomicAdd(&lhist[key(p.x)], 1); slab[pos] = p.x >> 8;
        pos = atomicAdd(&lhist[key(p.y)], 1); slab[pos] = p.y >> 8;
        pos = atomicAdd(&lhist[key(p.z)], 1); slab[pos] = p.z >> 8;
        pos = atomicAdd(&lhist[key(p.w)], 1); slab[pos] = p.w >> 8;
    }
    for (int j = cnt4 + t; j < cnt; j += 1024) {
        int p = part[start + j];
        int pos = atomicAdd(&lhist[key(p)], 1);
        slab[pos] = p >> 8;
    }
    __syncthreads();
    // deterministic order: each thread insertion-sorts its key's segment
    // (Poisson(8) sizes, worst ~28 — cheap). Duplicate (dst,src) edges are
    // identical entries, so ties cannot introduce nondeterminism.
    {
        int ge = lrow[t], gs = ge - v;
        for (int i = gs + 1; i < ge; i++) {
            int x = slab[i], j2 = i - 1;
            while (j2 >= gs && slab[j2] > x) { slab[j2 + 1] = slab[j2]; j2--; }
            slab[j2 + 1] = x;
        }
    }
    __syncthreads();
    for (int j = t; j < cnt; j += 1024) csr[start + j] = slab[j];
}

// ---------------- layer-2 gemm with fused branch attention ----------------
__global__ void gemm2_fused(const float* __restrict__ hbig, const float* __restrict__ fha,
                            const float* __restrict__ WA, const float* __restrict__ WB,
                            const float* __restrict__ asA, const float* __restrict__ adA,
                            const float* __restrict__ asB, const float* __restrict__ adB,
                            __half* __restrict__ h16, float* __restrict__ ssrc,
                            float* __restrict__ sdst, int N) {
    __shared__ float xs[4][4 * ND];
    int half = blockIdx.x & 1;
    int blk = blockIdx.x >> 1;
    int wave = threadIdx.x >> 6;
    int lane = threadIdx.x & 63;
    const float* W  = half ? WB : WA;
    const float* av_ = half ? asB : asA;
    const float* dv_ = half ? adB : adA;
    int nodeBase = (blk * 4 + wave) * 4;
    float* xsw = xs[wave];

    if (nodeBase < N) {
        int nd = nodeBase + (lane >> 4);           // node this lane stages
        int col = (lane & 15) * 4;
        float4 vi = *(const float4*)&hbig[(size_t)nd * ND + col];
        float4 vp = *(const float4*)&hbig[((size_t)N + nd) * ND + col];
        float4 a0 = *(const float4*)&fha[col];
        float4 a1 = *(const float4*)&fha[ND + col];
        float p0 = vi.x * a0.x + vi.y * a0.y + vi.z * a0.z + vi.w * a0.w;
        float p1 = vp.x * a1.x + vp.y * a1.y + vp.z * a1.z + vp.w * a1.w;
#pragma unroll
        for (int m = 1; m <= 8; m <<= 1) {
            p0 += __shfl_xor(p0, m, 64);
            p1 += __shfl_xor(p1, m, 64);
        }
        float mx = fmaxf(p0, p1);
        float e0 = __expf(p0 - mx), e1 = __expf(p1 - mx);
        float inv = 1.f / (e0 + e1);
        float4 f;
        f.x = (e0 * vi.x + e1 * vp.x) * inv;
        f.y = (e0 * vi.y + e1 * vp.y) * inv;
        f.z = (e0 * vi.z + e1 * vp.z) * inv;
        f.w = (e0 * vi.w + e1 * vp.w) * inv;
        *(float4*)&xsw[lane * 4] = f;
    }
    __syncthreads();
    if (nodeBase >= N) return;

    float4 acc = {0.f, 0.f, 0.f, 0.f};
#pragma unroll
    for (int k = 0; k < ND; k++) {
        float wv = W[k * ND + lane];
        acc.x = fmaf(xsw[0 * ND + k], wv, acc.x);
        acc.y = fmaf(xsw[1 * ND + k], wv, acc.y);
        acc.z = fmaf(xsw[2 * ND + k], wv, acc.z);
        acc.w = fmaf(xsw[3 * ND + k], wv, acc.w);
    }
    float av = av_[lane], dv = dv_[lane];
    float s1x = wave_sum(acc.x * av), s2x = wave_sum(acc.x * dv);
    float s1y = wave_sum(acc.y * av), s2y = wave_sum(acc.y * dv);
    float s1z = wave_sum(acc.z * av), s2z = wave_sum(acc.z * dv);
    float s1w = wave_sum(acc.w * av), s2w = wave_sum(acc.w * dv);

    int g0 = half * N + nodeBase;
    h16[(size_t)(g0 + 0) * ND + lane] = __float2half(acc.x);
    h16[(size_t)(g0 + 1) * ND + lane] = __float2half(acc.y);
    h16[(size_t)(g0 + 2) * ND + lane] = __float2half(acc.z);
    h16[(size_t)(g0 + 3) * ND + lane] = __float2half(acc.w);
    if (lane == 0) {
        ssrc[g0] = s1x; sdst[g0] = s2x;
        ssrc[g0 + 1] = s1y; sdst[g0 + 1] = s2y;
        ssrc[g0 + 2] = s1z; sdst[g0 + 2] = s2z;
        ssrc[g0 + 3] = s1w; sdst[g0 + 3] = s2w;
    }
}

// ---------------- dual-graph aggregate: 4 nodes/wave, depth-3 h-pipeline,
// chunk-level csr/score prefetch ----------------
__global__ void aggregate_dual(const int* __restrict__ csr, const int* __restrict__ row,
                               const int* __restrict__ deg, const float* __restrict__ ssrc,
                               const float* __restrict__ sdst, const __half* __restrict__ h16,
                               const float* __restrict__ bA, const float* __restrict__ bB,
                               float* __restrict__ out, int N, int relu) {
    int half = blockIdx.x & 1;
    int wave = threadIdx.x >> 6;
    int lane = threadIdx.x & 63;
    int sub  = lane >> 4;             // which of the 4 nodes this lane serves
    int l16  = lane & 15;             // lane within the 16-lane group
    int slot = l16 >> 3;              // edge slot 0/1
    int fl8  = (l16 & 7) * 8;         // 8 halves owned by this lane
    int node = ((blockIdx.x >> 1) * 4 + wave) * 4 + sub;   // within half
    bool valid = node < N;
    int g = half * N + node;
    const float* bias = half ? bB : bA;
    const float* ss = ssrc + (size_t)half * N;       // per-half score table
    const __half* hh = h16 + (size_t)half * N * ND;  // per-half feature table

    int start = valid ? row[g] : 0;
    int cnt   = valid ? deg[g] : 0;
    float sd  = valid ? sdst[g] : 0.f;
    float wself = valid ? __expf(lrelu(ss[node] + sd)) : 0.f;

    float acc[8] = {0.f, 0.f, 0.f, 0.f, 0.f, 0.f, 0.f, 0.f};
    float denomp = 0.f;
    int waveBase = sub << 4;          // first lane of this group in the wave

    // prologue: chunk 0 indices + scores
    int c16 = min(16, cnt);
    int sj = (l16 < c16) ? csr[start + l16] : 0;
    float wj = (l16 < c16) ? __expf(lrelu(ss[sj] + sd)) : 0.f;

    for (int base = 0; base < cnt; base += 16) {
        // prefetch next chunk's indices + raw scores before the c-steps
        int nb2 = base + 16;
        int sjn = 0; float svn = 0.f; int c16n = cnt - nb2;
        if (nb2 < cnt) {
            sjn = (l16 < c16n) ? csr[start + nb2 + l16] : 0;
            svn = (l16 < c16n) ? ss[sjn] : 0.f;
        }
        denomp += wj;
        int nq = (min(16, cnt - base) + 1) >> 1;
        // depth-3 pipeline: 2 h-gathers in flight
        float w0 = __shfl(wj, waveBase + slot, 64);
        int s0 = __shfl(sj, waveBase + slot, 64);
        int4 r0 = *(const int4*)(hh + (size_t)s0 * ND + fl8);
        if (nq > 1) {
            float w1 = __shfl(wj, waveBase + 2 + slot, 64);
            int s1 = __shfl(sj, waveBase + 2 + slot, 64);
            int4 r1 = *(const int4*)(hh + (size_t)s1 * ND + fl8);
            for (int c = 2; c < nq; c++) {
                float w2 = __shfl(wj, waveBase + c * 2 + slot, 64);
                int s2 = __shfl(sj, waveBase + c * 2 + slot, 64);
                int4 r2 = *(const int4*)(hh + (size_t)s2 * ND + fl8);
                fma8(acc, w0, r0);
                w0 = w1; r0 = r1;
                w1 = w2; r1 = r2;
            }
            fma8(acc, w0, r0);
            fma8(acc, w1, r1);
        } else {
            fma8(acc, w0, r0);
        }
        // finish next chunk's weights (exp after the latency-heavy phase)
        if (nb2 < cnt) {
            wj = (l16 < c16n) ? __expf(lrelu(svn + sd)) : 0.f;
            sj = sjn;
        }
    }

    // combine the 2 slots (single xor level)
#pragma unroll
    for (int i = 0; i < 8; i++) acc[i] += __shfl_xor(acc[i], 8, 64);
    // denom: sum over the 16-lane group
#pragma unroll
    for (int m = 1; m <= 8; m <<= 1) denomp += __shfl_xor(denomp, m, 64);
    float denom = denomp + wself;

    if (!valid || slot != 0) return;
    // self contribution + epilogue (8 lanes per group, 8 cols each)
    int4 rawS = *(const int4*)(hh + (size_t)node * ND + fl8);
    union { int4 i; __half h[8]; } us;
    us.i = rawS;
    float v[8];
#pragma unroll
    for (int i = 0; i < 8; i++)
        v[i] = (acc[i] + wself * __half2float(us.h[i])) / denom + bias[fl8 + i];
    if (relu) {
#pragma unroll
        for (int i = 0; i < 8; i++) v[i] = fmaxf(v[i], 0.f);
    }
    *(float4*)&out[(size_t)g * ND + fl8]     = make_float4(v[0], v[1], v[2], v[3]);
    *(float4*)&out[(size_t)g * ND + fl8 + 4] = make_float4(v[4], v[5], v[6], v[7]);
}

// branch attention + final 64->1 MLP
__global__ void branch_att_mlp(const float* __restrict__ hbig, const float* __restrict__ att,
                               const float* __restrict__ mlpw, const float* __restrict__ mlpb,
                               float* __restrict__ out, int n) {
    int gid = blockIdx.x * blockDim.x + threadIdx.x;
    int node = gid >> 6, lane = gid & 63;
    if (node >= n) return;
    float vi = hbig[(size_t)node * ND + lane];
    float vp = hbig[((size_t)n + node) * ND + lane];
    float s0 = wave_sum(att[lane] * vi);
    float s1 = wave_sum(att[ND + lane] * vp);
    float m = fmaxf(s0, s1);
    float a0 = __expf(s0 - m), a1 = __expf(s1 - m);
    float xj = (a0 * vi + a1 * vp) / (a0 + a1);
    float o = wave_sum(xj * mlpw[lane]);
    if (lane == 0) out[node] = o + mlpb[0];
}

extern "C" void kernel_launch(void* const* d_in, const int* in_sizes, int n_in,
                              void* d_out, int out_size, void* d_ws, size_t ws_size,
                              hipStream_t stream) {
    const int N = in_sizes[0] / ND;   // 50000
    const int E = in_sizes[2] / 2;    // 1600000

    const float* x_ind = (const float*)d_in[0];
    const float* x_pos = (const float*)d_in[1];
    const int*   e_ind = (const int*)d_in[2];
    const int*   e_pos = (const int*)d_in[3];
    const float* w1i = (const float*)d_in[4];
    const float* as1i = (const float*)d_in[5];
    const float* ad1i = (const float*)d_in[6];
    const float* b1i = (const float*)d_in[7];
    const float* w2i = (const float*)d_in[8];
    const float* as2i = (const float*)d_in[9];
    const float* ad2i = (const float*)d_in[10];
    const float* b2i = (const float*)d_in[11];
    const float* w1p = (const float*)d_in[12];
    const float* as1p = (const float*)d_in[13];
    const float* ad1p = (const float*)d_in[14];
    const float* b1p = (const float*)d_in[15];
    const float* w2p = (const float*)d_in[16];
    const float* as2p = (const float*)d_in[17];
    const float* ad2p = (const float*)d_in[18];
    const float* b2p = (const float*)d_in[19];
    const float* fha = (const float*)d_in[20];
    const float* attw = (const float*)d_in[21];
    const float* mlpw = (const float*)d_in[22];
    const float* mlpb = (const float*)d_in[23];

    char* ws = (char*)d_ws;
    size_t off = 0;
    auto alloc = [&](size_t elems) { void* p = ws + off; off += elems * 4; return p; };

    const int n2 = 2 * N;
    const int nb = (n2 + BG - 1) / BG;             // 391

    __half* h16 = (__half*)alloc((size_t)n2 * ND / 2);  // fp16 features both halves, 12.8 MB
    float* hbig = (float*)alloc((size_t)n2 * ND);       // layer outputs [I; P], 25.6 MB
    float* ssrc = (float*)alloc(n2);
    float* sdst = (float*)alloc(n2);
    int* deg    = (int*)alloc(n2);
    int* rowi   = (int*)alloc(n2);
    int* csr    = (int*)alloc((size_t)nb * CAP);        // 14.4 MB slabs
    int* bcursor= (int*)alloc(MAXB);
    // part[nb*CAP] ints alias hbig (25.6 MB >= 14.4 MB) — consumed by
    // bucket_build before the first aggregate_dual writes hbig
    int* part   = (int*)hbig;

    const int partBlocks  = (2 * E + PCH - 1) / PCH;        // 196
    const int gemm1Blocks = 2 * ((N + 63) / 64);            // 1564 (64 nodes/block/half)
    const int gemm2Blocks = 2 * ((N + 15) / 16);            // 6250
    const int aggBlocks   = 2 * ((N + 15) / 16);            // 6250
    const int nodeBlocks  = (N + 3) / 4;                    // 12500

    // ---- CSR build overlapped with layer-1 gemm (independent work) ----
    init_cursor<<<1, 512, 0, stream>>>(bcursor, nb);
    part_gemm<<<partBlocks + gemm1Blocks, 1024, 0, stream>>>(
        e_ind, e_pos, bcursor, part,
        x_ind, x_pos, w1i, w1p, as1i, ad1i, as1p, ad1p,
        h16, ssrc, sdst, N, E, nb, partBlocks);
    bucket_build<<<nb, 1024, 0, stream>>>(part, bcursor, rowi, deg, csr, n2, N);

    // ---- layer 1 aggregate ----
    aggregate_dual<<<aggBlocks, 256, 0, stream>>>(csr, rowi, deg, ssrc, sdst, h16,
                                                  b1i, b1p, hbig, N, 1);

    // ---- layer 2 (branch attention fused into the gemm) ----
    gemm2_fused<<<gemm2Blocks, 256, 0, stream>>>(hbig, fha, w2i, w2p,
                                                 as2i, ad2i, as2p, ad2p,
                                                 h16, ssrc, sdst, N);
    aggregate_dual<<<aggBlocks, 256, 0, stream>>>(csr, rowi, deg, ssrc, sdst, h16,
                                                  b2i, b2p, hbig, N, 0);
    branch_att_mlp<<<nodeBlocks, 256, 0, stream>>>(hbig, attw, mlpw, mlpb,
                                                   (float*)d_out, N);
}

// Round 2
// 343.582 us; speedup vs baseline: 1.0029x; 1.0029x over previous
//
#include <hip/hip_runtime.h>
#include <hip/hip_fp16.h>

#define ND 64
#define BG 128        // dst ids per bucket
#define MAXB 1024     // max buckets (LDS sizing); nb = ceil(2N/BG) = 782
#define PCH 16384     // edges per partition chunk: 196 part-blocks
#define CAP 4608      // per-bucket slab capacity; lambda=4096, sigma~64 -> 8-sigma margin

__device__ __forceinline__ float lrelu(float x) { return x > 0.f ? x : 0.2f * x; }

__device__ __forceinline__ float wave_sum(float v) {
#pragma unroll
    for (int m = 32; m > 0; m >>= 1) v += __shfl_xor(v, m, 64);
    return v;
}

// 8 fp16 x fp32 fused into 8 fp32 accumulators — scalar form so the compiler
// can emit v_fma_mix_f32 (fp16 source converted in the FMA, no separate cvt)
__device__ __forceinline__ void fma8(float* acc, float w, int4 raw) {
    union { int4 i; __half h[8]; } u;
    u.i = raw;
#pragma unroll
    for (int i = 0; i < 8; i++) acc[i] = fmaf(w, __half2float(u.h[i]), acc[i]);
}

// ---------------- bucketed CSR build (fixed-capacity slabs) ----------------
// combined dst index idx = graph*N + dst in [0, n2); bucket = idx >> 7.
// Bucket b owns part[b*CAP .. b*CAP+cnt) and csr[b*CAP .. b*CAP+cnt).

__global__ void init_cursor(int* __restrict__ bcursor, int nb) {
    int t = threadIdx.x;
    if (t < nb) bcursor[t] = t * CAP;
}

// ---- partition body: multi-split into reserved runs; entry (src<<8 | idx&255) ----
// Fast path (full chunk): 16 edges/thread stashed in registers across passes —
// pass 2 does zero global loads.
__device__ void partition_body(int* hist, int* lcur,
                               const int* __restrict__ eI, const int* __restrict__ eP,
                               int* __restrict__ bcursor, int* __restrict__ part,
                               int N, int E, int nb) {
    int t = threadIdx.x;
    int total = 2 * E;
    int chunkBase = blockIdx.x * PCH;
    int cnt = min(PCH, total - chunkBase);
    if (t < nb) hist[t] = 0;
    __syncthreads();

    if (cnt == PCH) {
        int pk[16];
        unsigned bkp[8];
#pragma unroll
        for (int it = 0; it < 4; it++) {
            int i = t * 4 + it * 4096;
            int e = chunkBase + i;
            int sv[4], dv[4];
            if (e + 3 < E) {
                int4 a = *(const int4*)(eI + e);
                int4 b = *(const int4*)(eI + E + e);
                sv[0] = a.x; sv[1] = a.y; sv[2] = a.z; sv[3] = a.w;
                dv[0] = b.x; dv[1] = b.y; dv[2] = b.z; dv[3] = b.w;
            } else if (e >= E) {
                int4 a = *(const int4*)(eP + (e - E));
                int4 b = *(const int4*)(eP + E + (e - E));
                sv[0] = a.x; sv[1] = a.y; sv[2] = a.z; sv[3] = a.w;
                dv[0] = b.x + N; dv[1] = b.y + N; dv[2] = b.z + N; dv[3] = b.w + N;
            } else {
#pragma unroll
                for (int k = 0; k < 4; k++) {
                    int ee = e + k;
                    if (ee < E) { sv[k] = eI[ee]; dv[k] = eI[E + ee]; }
                    else        { sv[k] = eP[ee - E]; dv[k] = N + eP[E + ee - E]; }
                }
            }
#pragma unroll
            for (int k = 0; k < 4; k++) {
                int j = it * 4 + k;
                int bk = dv[k] >> 7;
                pk[j] = (sv[k] << 8) | (dv[k] & 255);
                atomicAdd(&hist[bk], 1);
                if ((j & 1) == 0) bkp[j >> 1] = (unsigned)bk;
                else bkp[j >> 1] |= (unsigned)bk << 16;
            }
        }
        __syncthreads();
        if (t < nb) lcur[t] = hist[t] ? atomicAdd(&bcursor[t], hist[t]) : 0;
        __syncthreads();
#pragma unroll
        for (int j = 0; j < 16; j++) {
            int bk = (bkp[j >> 1] >> ((j & 1) * 16)) & 0xffff;
            int pos = atomicAdd(&lcur[bk], 1);
            part[pos] = pk[j];
        }
        return;
    }

    // slow path (tail chunk only)
    int cnt4 = cnt & ~3;
    for (int i = t * 4; i < cnt4; i += 4096) {
        int e = chunkBase + i;
        int4 d; int base;
        if (e + 3 < E)   { d = *(const int4*)(eI + E + e); base = 0; }
        else if (e >= E) { d = *(const int4*)(eP + E + (e - E)); base = N; }
        else {
            int tmp[4];
#pragma unroll
            for (int k = 0; k < 4; k++) {
                int ee = e + k;
                tmp[k] = (ee < E) ? eI[E + ee] : N + eP[E + ee - E];
            }
            d = make_int4(tmp[0], tmp[1], tmp[2], tmp[3]); base = 0;
        }
        atomicAdd(&hist[(base + d.x) >> 7], 1);
        atomicAdd(&hist[(base + d.y) >> 7], 1);
        atomicAdd(&hist[(base + d.z) >> 7], 1);
        atomicAdd(&hist[(base + d.w) >> 7], 1);
    }
    for (int i = cnt4 + t; i < cnt; i += 1024) {
        int e = chunkBase + i;
        int idx = (e < E) ? eI[E + e] : N + eP[E + (e - E)];
        atomicAdd(&hist[idx >> 7], 1);
    }
    __syncthreads();
    if (t < nb) lcur[t] = hist[t] ? atomicAdd(&bcursor[t], hist[t]) : 0;
    __syncthreads();
    for (int i = t; i < cnt; i += 1024) {
        int e = chunkBase + i;
        int s, idx;
        if (e < E) { s = eI[e]; idx = eI[E + e]; }
        else       { s = eP[e - E]; idx = N + eP[E + (e - E)]; }
        int pos = atomicAdd(&lcur[idx >> 7], 1);
        part[pos] = (s << 8) | (idx & 255);
    }
}

// ---- gemm body: h(fp16) = x @ W + score dots; 16 waves/block, 4 nodes/wave ----
__device__ void gemm_body(float* xsAll, int gb,
                          const float* __restrict__ xA, const float* __restrict__ xB,
                          const float* __restrict__ WA, const float* __restrict__ WB,
                          const float* __restrict__ asA, const float* __restrict__ adA,
                          const float* __restrict__ asB, const float* __restrict__ adB,
                          __half* __restrict__ h16, float* __restrict__ ssrc,
                          float* __restrict__ sdst, int N) {
    int half = gb & 1;
    int blk = gb >> 1;
    int wave = threadIdx.x >> 6;
    int lane = threadIdx.x & 63;
    const float* x  = half ? xB : xA;
    const float* W  = half ? WB : WA;
    const float* av_ = half ? asB : asA;
    const float* dv_ = half ? adB : adA;
    int nodeBase = (blk * 16 + wave) * 4;      // within half
    float* xs = xsAll + wave * (4 * ND);

    if (nodeBase + 3 < N) {
        *(float4*)&xs[lane * 4] = *(const float4*)&x[(size_t)nodeBase * ND + lane * 4];
    } else if (nodeBase < N) {
#pragma unroll
        for (int i = 0; i < 4; i++) {
            int gi = nodeBase * ND + lane * 4 + i;
            xs[lane * 4 + i] = (gi < N * ND) ? x[gi] : 0.f;
        }
    }
    __syncthreads();
    if (nodeBase >= N) return;

    float4 acc = {0.f, 0.f, 0.f, 0.f};
#pragma unroll
    for (int k = 0; k < ND; k++) {
        float wv = W[k * ND + lane];
        acc.x = fmaf(xs[0 * ND + k], wv, acc.x);
        acc.y = fmaf(xs[1 * ND + k], wv, acc.y);
        acc.z = fmaf(xs[2 * ND + k], wv, acc.z);
        acc.w = fmaf(xs[3 * ND + k], wv, acc.w);
    }
    float av = av_[lane], dv = dv_[lane];
    float s1x = wave_sum(acc.x * av), s2x = wave_sum(acc.x * dv);
    float s1y = wave_sum(acc.y * av), s2y = wave_sum(acc.y * dv);
    float s1z = wave_sum(acc.z * av), s2z = wave_sum(acc.z * dv);
    float s1w = wave_sum(acc.w * av), s2w = wave_sum(acc.w * dv);

    int g0 = half * N + nodeBase;
    h16[(size_t)(g0 + 0) * ND + lane] = __float2half(acc.x);
    if (nodeBase + 1 < N) h16[(size_t)(g0 + 1) * ND + lane] = __float2half(acc.y);
    if (nodeBase + 2 < N) h16[(size_t)(g0 + 2) * ND + lane] = __float2half(acc.z);
    if (nodeBase + 3 < N) h16[(size_t)(g0 + 3) * ND + lane] = __float2half(acc.w);
    if (lane == 0) {
        ssrc[g0] = s1x; sdst[g0] = s2x;
        if (nodeBase + 1 < N) { ssrc[g0 + 1] = s1y; sdst[g0 + 1] = s2y; }
        if (nodeBase + 2 < N) { ssrc[g0 + 2] = s1z; sdst[g0 + 2] = s2z; }
        if (nodeBase + 3 < N) { ssrc[g0 + 3] = s1w; sdst[g0 + 3] = s2w; }
    }
}

// ---- fused: partition (blocks < partBlocks) | layer-1 gemm (the rest) ----
__global__ void __launch_bounds__(1024) part_gemm(
        const int* __restrict__ eI, const int* __restrict__ eP,
        int* __restrict__ bcursor, int* __restrict__ part,
        const float* __restrict__ xA, const float* __restrict__ xB,
        const float* __restrict__ WA, const float* __restrict__ WB,
        const float* __restrict__ asA, const float* __restrict__ adA,
        const float* __restrict__ asB, const float* __restrict__ adB,
        __half* __restrict__ h16, float* __restrict__ ssrc, float* __restrict__ sdst,
        int N, int E, int nb, int partBlocks) {
    __shared__ int smem[16 * 4 * ND];   // 16 KB: part uses 8 KB (hist+lcur); gemm uses all
    if (blockIdx.x < partBlocks) {
        partition_body(smem, smem + MAXB, eI, eP, bcursor, part, N, E, nb);
    } else {
        gemm_body((float*)smem, blockIdx.x - partBlocks,
                  xA, xB, WA, WB, asA, adA, asB, adB, h16, ssrc, sdst, N);
    }
}

// one block (1024 thr) per bucket: per-(dst,src-octile) hist + scan -> row/deg,
// LDS-slab scatter + per-key insertion sort by src id (octile is monotone in
// src, so rows come out fully src-sorted => csr is BIT-DETERMINISTIC regardless
// of atomic scatter order), then coalesced copy-out.
__global__ void bucket_build(const int* __restrict__ part, const int* __restrict__ bcursor,
                             int* __restrict__ row, int* __restrict__ deg,
                             int* __restrict__ csr, int n2, int N) {
    __shared__ int lhist[BG * 8];     // 1024 keys: dstLow*8 + srcOctile
    __shared__ int lrow[BG * 8];
    __shared__ int slab[CAP];         // 18 KB staging for deterministic sort
    int b = blockIdx.x, t = threadIdx.x;   // blockDim == 1024
    int start = b * CAP;
    int cnt = min(bcursor[b] - start, CAP);
    int cnt4 = cnt & ~3;
    int t1 = (N * 1) >> 3, t2 = (N * 2) >> 3, t3 = (N * 3) >> 3, t4 = (N * 4) >> 3;
    int t5 = (N * 5) >> 3, t6 = (N * 6) >> 3, t7 = (N * 7) >> 3;
    auto key = [&](int p) {
        int s = p >> 8;
        int o = (s >= t1) + (s >= t2) + (s >= t3) + (s >= t4)
              + (s >= t5) + (s >= t6) + (s >= t7);
        return ((p & 127) << 3) | o;
    };
    lhist[t] = 0;
    __syncthreads();
    for (int j = t * 4; j < cnt4; j += 4096) {
        int4 p = *(const int4*)(part + start + j);
        atomicAdd(&lhist[key(p.x)], 1);
        atomicAdd(&lhist[key(p.y)], 1);
        atomicAdd(&lhist[key(p.z)], 1);
        atomicAdd(&lhist[key(p.w)], 1);
    }
    for (int j = cnt4 + t; j < cnt; j += 1024) atomicAdd(&lhist[key(part[start + j])], 1);
    __syncthreads();
    int v = lhist[t];
    lrow[t] = v;
    __syncthreads();
    for (int off = 1; off < 1024; off <<= 1) {
        int a = (t >= off) ? lrow[t - off] : 0;
        __syncthreads();
        lrow[t] += a;
        __syncthreads();
    }
    // lrow = inclusive scan; key t's slab-relative segment = [lrow[t]-v, lrow[t])
    if (t < BG) {
        int g = b * BG + t;
        if (g < n2) {
            row[g] = start + lrow[8 * t] - lhist[8 * t];
            int d = 0;
#pragma unroll
            for (int i = 0; i < 8; i++) d += lhist[8 * t + i];
            deg[g] = d;
        }
    }
    __syncthreads();
    lhist[t] = lrow[t] - v;           // reuse as LDS-relative write cursor
    __syncthreads();
    for (int j = t * 4; j < cnt4; j += 4096) {
        int4 p = *(const int4*)(part + start + j);
        int pos;
        pos = atomicAdd(&lhist[key(p.x)], 1); slab[pos] = p.x >> 8;
        pos = atomicAdd(&lhist[key(p.y)], 1); slab[pos] = p.y >> 8;
        pos = atomicAdd(&lhist[key(p.z)], 1); slab[pos] = p.z >> 8;
        pos = atomicAdd(&lhist[key(p.w)], 1); slab[pos] = p.w >> 8;
    }
    for (int j = cnt4 + t; j < cnt; j += 1024) {
        int p = part[start + j];
        int pos = atomicAdd(&lhist[key(p)], 1);
        slab[pos] = p >> 8;
    }
    __syncthreads();
    // deterministic order: each thread insertion-sorts its key's segment
    // (Poisson(4) sizes, worst ~16 — cheap). Duplicate (dst,src) edges are
    // identical entries, so ties cannot introduce nondeterminism.
    {
        int ge = lrow[t], gs = ge - v;
        for (int i = gs + 1; i < ge; i++) {
            int x = slab[i], j2 = i - 1;
            while (j2 >= gs && slab[j2] > x) { slab[j2 + 1] = slab[j2]; j2--; }
            slab[j2 + 1] = x;
        }
    }
    __syncthreads();
    for (int j = t; j < cnt; j += 1024) csr[start + j] = slab[j];
}

// ---------------- layer-2 gemm with fused branch attention ----------------
__global__ void gemm2_fused(const float* __restrict__ hbig, const float* __restrict__ fha,
                            const float* __restrict__ WA, const float* __restrict__ WB,
                            const float* __restrict__ asA, const float* __restrict__ adA,
                            const float* __restrict__ asB, const float* __restrict__ adB,
                            __half* __restrict__ h16, float* __restrict__ ssrc,
                            float* __restrict__ sdst, int N) {
    __shared__ float xs[4][4 * ND];
    int half = blockIdx.x & 1;
    int blk = blockIdx.x >> 1;
    int wave = threadIdx.x >> 6;
    int lane = threadIdx.x & 63;
    const float* W  = half ? WB : WA;
    const float* av_ = half ? asB : asA;
    const float* dv_ = half ? adB : adA;
    int nodeBase = (blk * 4 + wave) * 4;
    float* xsw = xs[wave];

    if (nodeBase < N) {
        int nd = nodeBase + (lane >> 4);           // node this lane stages
        int col = (lane & 15) * 4;
        float4 vi = *(const float4*)&hbig[(size_t)nd * ND + col];
        float4 vp = *(const float4*)&hbig[((size_t)N + nd) * ND + col];
        float4 a0 = *(const float4*)&fha[col];
        float4 a1 = *(const float4*)&fha[ND + col];
        float p0 = vi.x * a0.x + vi.y * a0.y + vi.z * a0.z + vi.w * a0.w;
        float p1 = vp.x * a1.x + vp.y * a1.y + vp.z * a1.z + vp.w * a1.w;
#pragma unroll
        for (int m = 1; m <= 8; m <<= 1) {
            p0 += __shfl_xor(p0, m, 64);
            p1 += __shfl_xor(p1, m, 64);
        }
        float mx = fmaxf(p0, p1);
        float e0 = __expf(p0 - mx), e1 = __expf(p1 - mx);
        float inv = 1.f / (e0 + e1);
        float4 f;
        f.x = (e0 * vi.x + e1 * vp.x) * inv;
        f.y = (e0 * vi.y + e1 * vp.y) * inv;
        f.z = (e0 * vi.z + e1 * vp.z) * inv;
        f.w = (e0 * vi.w + e1 * vp.w) * inv;
        *(float4*)&xsw[lane * 4] = f;
    }
    __syncthreads();
    if (nodeBase >= N) return;

    float4 acc = {0.f, 0.f, 0.f, 0.f};
#pragma unroll
    for (int k = 0; k < ND; k++) {
        float wv = W[k * ND + lane];
        acc.x = fmaf(xsw[0 * ND + k], wv, acc.x);
        acc.y = fmaf(xsw[1 * ND + k], wv, acc.y);
        acc.z = fmaf(xsw[2 * ND + k], wv, acc.z);
        acc.w = fmaf(xsw[3 * ND + k], wv, acc.w);
    }
    float av = av_[lane], dv = dv_[lane];
    float s1x = wave_sum(acc.x * av), s2x = wave_sum(acc.x * dv);
    float s1y = wave_sum(acc.y * av), s2y = wave_sum(acc.y * dv);
    float s1z = wave_sum(acc.z * av), s2z = wave_sum(acc.z * dv);
    float s1w = wave_sum(acc.w * av), s2w = wave_sum(acc.w * dv);

    int g0 = half * N + nodeBase;
    h16[(size_t)(g0 + 0) * ND + lane] = __float2half(acc.x);
    h16[(size_t)(g0 + 1) * ND + lane] = __float2half(acc.y);
    h16[(size_t)(g0 + 2) * ND + lane] = __float2half(acc.z);
    h16[(size_t)(g0 + 3) * ND + lane] = __float2half(acc.w);
    if (lane == 0) {
        ssrc[g0] = s1x; sdst[g0] = s2x;
        ssrc[g0 + 1] = s1y; sdst[g0 + 1] = s2y;
        ssrc[g0 + 2] = s1z; sdst[g0 + 2] = s2z;
        ssrc[g0 + 3] = s1w; sdst[g0 + 3] = s2w;
    }
}

// ---------------- dual-graph aggregate: 4 nodes/wave, 32-edge chunks,
// depth-4 h-pipeline (3 gathers in flight), chunk-level csr/score prefetch ----
__global__ void aggregate_dual(const int* __restrict__ csr, const int* __restrict__ row,
                               const int* __restrict__ deg, const float* __restrict__ ssrc,
                               const float* __restrict__ sdst, const __half* __restrict__ h16,
                               const float* __restrict__ bA, const float* __restrict__ bB,
                               float* __restrict__ out, int N, int relu) {
    int half = blockIdx.x & 1;
    int wave = threadIdx.x >> 6;
    int lane = threadIdx.x & 63;
    int sub  = lane >> 4;             // which of the 4 nodes this lane serves
    int l16  = lane & 15;             // lane within the 16-lane group
    int slot = l16 >> 3;              // edge slot 0/1
    int fl8  = (l16 & 7) * 8;         // 8 halves owned by this lane
    int node = ((blockIdx.x >> 1) * 4 + wave) * 4 + sub;   // within half
    bool valid = node < N;
    int g = half * N + node;
    const float* bias = half ? bB : bA;
    const float* ss = ssrc + (size_t)half * N;       // per-half score table
    const __half* hh = h16 + (size_t)half * N * ND;  // per-half feature table

    int start = valid ? row[g] : 0;
    int cnt   = valid ? deg[g] : 0;
    float sd  = valid ? sdst[g] : 0.f;
    float wself = valid ? __expf(lrelu(ss[node] + sd)) : 0.f;

    float acc[8] = {0.f, 0.f, 0.f, 0.f, 0.f, 0.f, 0.f, 0.f};
    float denomp = 0.f;
    int waveBase = sub << 4;          // first lane of this group in the wave

    // prologue: chunk 0 (32 edges; two 16-wide csr/score loads per 16 lanes)
    int c0 = min(16, cnt), c1 = min(16, cnt - 16);
    int sj0 = (l16 < c0) ? csr[start + l16] : 0;
    int sj1 = (l16 < c1) ? csr[start + 16 + l16] : 0;
    float wj0 = (l16 < c0) ? __expf(lrelu(ss[sj0] + sd)) : 0.f;
    float wj1 = (l16 < c1) ? __expf(lrelu(ss[sj1] + sd)) : 0.f;

    // fetch weight+src for pipeline step c (edge e = 2c+slot within chunk);
    // selector (c>=8) is wave-uniform, so the shuffle source is well-defined
    auto fetchW = [&](int c, float& w, int& s) {
        float wv = (c >= 8) ? wj1 : wj0;
        int   sv = (c >= 8) ? sj1 : sj0;
        int e = 2 * c + slot;
        int sl = waveBase + (e & 15);
        w = __shfl(wv, sl, 64);
        s = __shfl(sv, sl, 64);
    };

    for (int base = 0; base < cnt; base += 32) {
        // prefetch next chunk's indices + raw scores before the c-steps
        int nb2 = base + 32;
        int sn0 = 0, sn1 = 0; float v0 = 0.f, v1 = 0.f;
        int d0 = cnt - nb2, d1 = cnt - nb2 - 16;
        if (nb2 < cnt) {
            sn0 = (l16 < d0) ? csr[start + nb2 + l16] : 0;
            v0  = (l16 < d0) ? ss[sn0] : 0.f;
            sn1 = (l16 < d1) ? csr[start + nb2 + 16 + l16] : 0;
            v1  = (l16 < d1) ? ss[sn1] : 0.f;
        }
        denomp += wj0 + wj1;
        int nq = (min(32, cnt - base) + 1) >> 1;
        // depth-4 pipeline: 3 h-gathers in flight
        float w0, w1, w2; int s0, s1, s2;
        fetchW(0, w0, s0);
        int4 r0 = *(const int4*)(hh + (size_t)s0 * ND + fl8);
        if (nq > 2) {
            fetchW(1, w1, s1);
            int4 r1 = *(const int4*)(hh + (size_t)s1 * ND + fl8);
            fetchW(2, w2, s2);
            int4 r2 = *(const int4*)(hh + (size_t)s2 * ND + fl8);
            for (int c = 3; c < nq; c++) {
                float w3; int s3;
                fetchW(c, w3, s3);
                int4 r3 = *(const int4*)(hh + (size_t)s3 * ND + fl8);
                fma8(acc, w0, r0);
                w0 = w1; r0 = r1;
                w1 = w2; r1 = r2;
                w2 = w3; r2 = r3;
            }
            fma8(acc, w0, r0);
            fma8(acc, w1, r1);
            fma8(acc, w2, r2);
        } else if (nq == 2) {
            fetchW(1, w1, s1);
            int4 r1 = *(const int4*)(hh + (size_t)s1 * ND + fl8);
            fma8(acc, w0, r0);
            fma8(acc, w1, r1);
        } else {
            fma8(acc, w0, r0);
        }
        // finish next chunk's weights (exp after the latency-heavy phase)
        if (nb2 < cnt) {
            wj0 = (l16 < d0) ? __expf(lrelu(v0 + sd)) : 0.f; sj0 = sn0;
            wj1 = (l16 < d1) ? __expf(lrelu(v1 + sd)) : 0.f; sj1 = sn1;
        }
    }

    // combine the 2 slots (single xor level)
#pragma unroll
    for (int i = 0; i < 8; i++) acc[i] += __shfl_xor(acc[i], 8, 64);
    // denom: sum over the 16-lane group
#pragma unroll
    for (int m = 1; m <= 8; m <<= 1) denomp += __shfl_xor(denomp, m, 64);
    float denom = denomp + wself;

    if (!valid || slot != 0) return;
    // self contribution + epilogue (8 lanes per group, 8 cols each)
    int4 rawS = *(const int4*)(hh + (size_t)node * ND + fl8);
    union { int4 i; __half h[8]; } us;
    us.i = rawS;
    float v[8];
#pragma unroll
    for (int i = 0; i < 8; i++)
        v[i] = (acc[i] + wself * __half2float(us.h[i])) / denom + bias[fl8 + i];
    if (relu) {
#pragma unroll
        for (int i = 0; i < 8; i++) v[i] = fmaxf(v[i], 0.f);
    }
    *(float4*)&out[(size_t)g * ND + fl8]     = make_float4(v[0], v[1], v[2], v[3]);
    *(float4*)&out[(size_t)g * ND + fl8 + 4] = make_float4(v[4], v[5], v[6], v[7]);
}

// branch attention + final 64->1 MLP
__global__ void branch_att_mlp(const float* __restrict__ hbig, const float* __restrict__ att,
                               const float* __restrict__ mlpw, const float* __restrict__ mlpb,
                               float* __restrict__ out, int n) {
    int gid = blockIdx.x * blockDim.x + threadIdx.x;
    int node = gid >> 6, lane = gid & 63;
    if (node >= n) return;
    float vi = hbig[(size_t)node * ND + lane];
    float vp = hbig[((size_t)n + node) * ND + lane];
    float s0 = wave_sum(att[lane] * vi);
    float s1 = wave_sum(att[ND + lane] * vp);
    float m = fmaxf(s0, s1);
    float a0 = __expf(s0 - m), a1 = __expf(s1 - m);
    float xj = (a0 * vi + a1 * vp) / (a0 + a1);
    float o = wave_sum(xj * mlpw[lane]);
    if (lane == 0) out[node] = o + mlpb[0];
}

extern "C" void kernel_launch(void* const* d_in, const int* in_sizes, int n_in,
                              void* d_out, int out_size, void* d_ws, size_t ws_size,
                              hipStream_t stream) {
    const int N = in_sizes[0] / ND;   // 50000
    const int E = in_sizes[2] / 2;    // 1600000

    const float* x_ind = (const float*)d_in[0];
    const float* x_pos = (const float*)d_in[1];
    const int*   e_ind = (const int*)d_in[2];
    const int*   e_pos = (const int*)d_in[3];
    const float* w1i = (const float*)d_in[4];
    const float* as1i = (const float*)d_in[5];
    const float* ad1i = (const float*)d_in[6];
    const float* b1i = (const float*)d_in[7];
    const float* w2i = (const float*)d_in[8];
    const float* as2i = (const float*)d_in[9];
    const float* ad2i = (const float*)d_in[10];
    const float* b2i = (const float*)d_in[11];
    const float* w1p = (const float*)d_in[12];
    const float* as1p = (const float*)d_in[13];
    const float* ad1p = (const float*)d_in[14];
    const float* b1p = (const float*)d_in[15];
    const float* w2p = (const float*)d_in[16];
    const float* as2p = (const float*)d_in[17];
    const float* ad2p = (const float*)d_in[18];
    const float* b2p = (const float*)d_in[19];
    const float* fha = (const float*)d_in[20];
    const float* attw = (const float*)d_in[21];
    const float* mlpw = (const float*)d_in[22];
    const float* mlpb = (const float*)d_in[23];

    char* ws = (char*)d_ws;
    size_t off = 0;
    auto alloc = [&](size_t elems) { void* p = ws + off; off += elems * 4; return p; };

    const int n2 = 2 * N;
    const int nb = (n2 + BG - 1) / BG;             // 782

    __half* h16 = (__half*)alloc((size_t)n2 * ND / 2);  // fp16 features both halves, 12.8 MB
    float* hbig = (float*)alloc((size_t)n2 * ND);       // layer outputs [I; P], 25.6 MB
    float* ssrc = (float*)alloc(n2);
    float* sdst = (float*)alloc(n2);
    int* deg    = (int*)alloc(n2);
    int* rowi   = (int*)alloc(n2);
    int* csr    = (int*)alloc((size_t)nb * CAP);        // 14.4 MB slabs
    int* bcursor= (int*)alloc(MAXB);
    // part[nb*CAP] ints alias hbig (25.6 MB >= 14.4 MB) — consumed by
    // bucket_build before the first aggregate_dual writes hbig
    int* part   = (int*)hbig;

    const int partBlocks  = (2 * E + PCH - 1) / PCH;        // 196
    const int gemm1Blocks = 2 * ((N + 63) / 64);            // 1564 (64 nodes/block/half)
    const int gemm2Blocks = 2 * ((N + 15) / 16);            // 6250
    const int aggBlocks   = 2 * ((N + 15) / 16);            // 6250
    const int nodeBlocks  = (N + 3) / 4;                    // 12500

    // ---- CSR build overlapped with layer-1 gemm (independent work) ----
    init_cursor<<<1, 1024, 0, stream>>>(bcursor, nb);
    part_gemm<<<partBlocks + gemm1Blocks, 1024, 0, stream>>>(
        e_ind, e_pos, bcursor, part,
        x_ind, x_pos, w1i, w1p, as1i, ad1i, as1p, ad1p,
        h16, ssrc, sdst, N, E, nb, partBlocks);
    bucket_build<<<nb, 1024, 0, stream>>>(part, bcursor, rowi, deg, csr, n2, N);

    // ---- layer 1 aggregate ----
    aggregate_dual<<<aggBlocks, 256, 0, stream>>>(csr, rowi, deg, ssrc, sdst, h16,
                                                  b1i, b1p, hbig, N, 1);

    // ---- layer 2 (branch attention fused into the gemm) ----
    gemm2_fused<<<gemm2Blocks, 256, 0, stream>>>(hbig, fha, w2i, w2p,
                                                 as2i, ad2i, as2p, ad2p,
                                                 h16, ssrc, sdst, N);
    aggregate_dual<<<aggBlocks, 256, 0, stream>>>(csr, rowi, deg, ssrc, sdst, h16,
                                                  b2i, b2p, hbig, N, 0);
    branch_att_mlp<<<nodeBlocks, 256, 0, stream>>>(hbig, attw, mlpw, mlpb,
                                                   (float*)d_out, N);
}

// Round 3
// 337.870 us; speedup vs baseline: 1.0199x; 1.0169x over previous
//
#include <hip/hip_runtime.h>
#include <hip/hip_fp16.h>

#define ND 64
#define BG 128        // dst ids per bucket
#define MAXB 1024     // max buckets (LDS sizing); nb = ceil(2N/BG) = 782
#define PCH 16384     // edges per partition chunk: 196 part-blocks
#define CAP 4608      // per-bucket slab capacity; lambda=4096, sigma~64 -> 8-sigma margin

__device__ __forceinline__ float lrelu(float x) { return x > 0.f ? x : 0.2f * x; }

__device__ __forceinline__ float wave_sum(float v) {
#pragma unroll
    for (int m = 32; m > 0; m >>= 1) v += __shfl_xor(v, m, 64);
    return v;
}

// 8 fp16 x fp32 fused into 8 fp32 accumulators — scalar form so the compiler
// can emit v_fma_mix_f32 (fp16 source converted in the FMA, no separate cvt)
__device__ __forceinline__ void fma8(float* acc, float w, int4 raw) {
    union { int4 i; __half h[8]; } u;
    u.i = raw;
#pragma unroll
    for (int i = 0; i < 8; i++) acc[i] = fmaf(w, __half2float(u.h[i]), acc[i]);
}

// ---------------- bucketed CSR build (fixed-capacity slabs) ----------------
// combined dst index idx = graph*N + dst in [0, n2); bucket = idx >> 7.
// Bucket b owns part[b*CAP .. b*CAP+cnt) and csr[b*CAP .. b*CAP+cnt).

__global__ void init_cursor(int* __restrict__ bcursor, int nb) {
    int t = threadIdx.x;
    if (t < nb) bcursor[t] = t * CAP;
}

// ---- partition body: multi-split into reserved runs; entry (src<<8 | idx&255) ----
// Fast path (full chunk): 16 edges/thread stashed in registers across passes —
// pass 2 does zero global loads.
__device__ void partition_body(int* hist, int* lcur,
                               const int* __restrict__ eI, const int* __restrict__ eP,
                               int* __restrict__ bcursor, int* __restrict__ part,
                               int N, int E, int nb) {
    int t = threadIdx.x;
    int total = 2 * E;
    int chunkBase = blockIdx.x * PCH;
    int cnt = min(PCH, total - chunkBase);
    if (t < nb) hist[t] = 0;
    __syncthreads();

    if (cnt == PCH) {
        int pk[16];
        unsigned bkp[8];
#pragma unroll
        for (int it = 0; it < 4; it++) {
            int i = t * 4 + it * 4096;
            int e = chunkBase + i;
            int sv[4], dv[4];
            if (e + 3 < E) {
                int4 a = *(const int4*)(eI + e);
                int4 b = *(const int4*)(eI + E + e);
                sv[0] = a.x; sv[1] = a.y; sv[2] = a.z; sv[3] = a.w;
                dv[0] = b.x; dv[1] = b.y; dv[2] = b.z; dv[3] = b.w;
            } else if (e >= E) {
                int4 a = *(const int4*)(eP + (e - E));
                int4 b = *(const int4*)(eP + E + (e - E));
                sv[0] = a.x; sv[1] = a.y; sv[2] = a.z; sv[3] = a.w;
                dv[0] = b.x + N; dv[1] = b.y + N; dv[2] = b.z + N; dv[3] = b.w + N;
            } else {
#pragma unroll
                for (int k = 0; k < 4; k++) {
                    int ee = e + k;
                    if (ee < E) { sv[k] = eI[ee]; dv[k] = eI[E + ee]; }
                    else        { sv[k] = eP[ee - E]; dv[k] = N + eP[E + ee - E]; }
                }
            }
#pragma unroll
            for (int k = 0; k < 4; k++) {
                int j = it * 4 + k;
                int bk = dv[k] >> 7;
                pk[j] = (sv[k] << 8) | (dv[k] & 255);
                atomicAdd(&hist[bk], 1);
                if ((j & 1) == 0) bkp[j >> 1] = (unsigned)bk;
                else bkp[j >> 1] |= (unsigned)bk << 16;
            }
        }
        __syncthreads();
        if (t < nb) lcur[t] = hist[t] ? atomicAdd(&bcursor[t], hist[t]) : 0;
        __syncthreads();
#pragma unroll
        for (int j = 0; j < 16; j++) {
            int bk = (bkp[j >> 1] >> ((j & 1) * 16)) & 0xffff;
            int pos = atomicAdd(&lcur[bk], 1);
            part[pos] = pk[j];
        }
        return;
    }

    // slow path (tail chunk only)
    int cnt4 = cnt & ~3;
    for (int i = t * 4; i < cnt4; i += 4096) {
        int e = chunkBase + i;
        int4 d; int base;
        if (e + 3 < E)   { d = *(const int4*)(eI + E + e); base = 0; }
        else if (e >= E) { d = *(const int4*)(eP + E + (e - E)); base = N; }
        else {
            int tmp[4];
#pragma unroll
            for (int k = 0; k < 4; k++) {
                int ee = e + k;
                tmp[k] = (ee < E) ? eI[E + ee] : N + eP[E + ee - E];
            }
            d = make_int4(tmp[0], tmp[1], tmp[2], tmp[3]); base = 0;
        }
        atomicAdd(&hist[(base + d.x) >> 7], 1);
        atomicAdd(&hist[(base + d.y) >> 7], 1);
        atomicAdd(&hist[(base + d.z) >> 7], 1);
        atomicAdd(&hist[(base + d.w) >> 7], 1);
    }
    for (int i = cnt4 + t; i < cnt; i += 1024) {
        int e = chunkBase + i;
        int idx = (e < E) ? eI[E + e] : N + eP[E + (e - E)];
        atomicAdd(&hist[idx >> 7], 1);
    }
    __syncthreads();
    if (t < nb) lcur[t] = hist[t] ? atomicAdd(&bcursor[t], hist[t]) : 0;
    __syncthreads();
    for (int i = t; i < cnt; i += 1024) {
        int e = chunkBase + i;
        int s, idx;
        if (e < E) { s = eI[e]; idx = eI[E + e]; }
        else       { s = eP[e - E]; idx = N + eP[E + (e - E)]; }
        int pos = atomicAdd(&lcur[idx >> 7], 1);
        part[pos] = (s << 8) | (idx & 255);
    }
}

// ---- gemm body: h(fp16) = x @ W + score dots; 16 waves/block, 4 nodes/wave ----
__device__ void gemm_body(float* xsAll, int gb,
                          const float* __restrict__ xA, const float* __restrict__ xB,
                          const float* __restrict__ WA, const float* __restrict__ WB,
                          const float* __restrict__ asA, const float* __restrict__ adA,
                          const float* __restrict__ asB, const float* __restrict__ adB,
                          __half* __restrict__ h16, float* __restrict__ ssrc,
                          float* __restrict__ sdst, int N) {
    int half = gb & 1;
    int blk = gb >> 1;
    int wave = threadIdx.x >> 6;
    int lane = threadIdx.x & 63;
    const float* x  = half ? xB : xA;
    const float* W  = half ? WB : WA;
    const float* av_ = half ? asB : asA;
    const float* dv_ = half ? adB : adA;
    int nodeBase = (blk * 16 + wave) * 4;      // within half
    float* xs = xsAll + wave * (4 * ND);

    if (nodeBase + 3 < N) {
        *(float4*)&xs[lane * 4] = *(const float4*)&x[(size_t)nodeBase * ND + lane * 4];
    } else if (nodeBase < N) {
#pragma unroll
        for (int i = 0; i < 4; i++) {
            int gi = nodeBase * ND + lane * 4 + i;
            xs[lane * 4 + i] = (gi < N * ND) ? x[gi] : 0.f;
        }
    }
    __syncthreads();
    if (nodeBase >= N) return;

    float4 acc = {0.f, 0.f, 0.f, 0.f};
#pragma unroll
    for (int k = 0; k < ND; k++) {
        float wv = W[k * ND + lane];
        acc.x = fmaf(xs[0 * ND + k], wv, acc.x);
        acc.y = fmaf(xs[1 * ND + k], wv, acc.y);
        acc.z = fmaf(xs[2 * ND + k], wv, acc.z);
        acc.w = fmaf(xs[3 * ND + k], wv, acc.w);
    }
    float av = av_[lane], dv = dv_[lane];
    float s1x = wave_sum(acc.x * av), s2x = wave_sum(acc.x * dv);
    float s1y = wave_sum(acc.y * av), s2y = wave_sum(acc.y * dv);
    float s1z = wave_sum(acc.z * av), s2z = wave_sum(acc.z * dv);
    float s1w = wave_sum(acc.w * av), s2w = wave_sum(acc.w * dv);

    int g0 = half * N + nodeBase;
    h16[(size_t)(g0 + 0) * ND + lane] = __float2half(acc.x);
    if (nodeBase + 1 < N) h16[(size_t)(g0 + 1) * ND + lane] = __float2half(acc.y);
    if (nodeBase + 2 < N) h16[(size_t)(g0 + 2) * ND + lane] = __float2half(acc.z);
    if (nodeBase + 3 < N) h16[(size_t)(g0 + 3) * ND + lane] = __float2half(acc.w);
    if (lane == 0) {
        ssrc[g0] = s1x; sdst[g0] = s2x;
        if (nodeBase + 1 < N) { ssrc[g0 + 1] = s1y; sdst[g0 + 1] = s2y; }
        if (nodeBase + 2 < N) { ssrc[g0 + 2] = s1z; sdst[g0 + 2] = s2z; }
        if (nodeBase + 3 < N) { ssrc[g0 + 3] = s1w; sdst[g0 + 3] = s2w; }
    }
}

// ---- fused: partition (blocks < partBlocks) | layer-1 gemm (the rest) ----
__global__ void __launch_bounds__(1024) part_gemm(
        const int* __restrict__ eI, const int* __restrict__ eP,
        int* __restrict__ bcursor, int* __restrict__ part,
        const float* __restrict__ xA, const float* __restrict__ xB,
        const float* __restrict__ WA, const float* __restrict__ WB,
        const float* __restrict__ asA, const float* __restrict__ adA,
        const float* __restrict__ asB, const float* __restrict__ adB,
        __half* __restrict__ h16, float* __restrict__ ssrc, float* __restrict__ sdst,
        int N, int E, int nb, int partBlocks) {
    __shared__ int smem[16 * 4 * ND];   // 16 KB: part uses 8 KB (hist+lcur); gemm uses all
    if (blockIdx.x < partBlocks) {
        partition_body(smem, smem + MAXB, eI, eP, bcursor, part, N, E, nb);
    } else {
        gemm_body((float*)smem, blockIdx.x - partBlocks,
                  xA, xB, WA, WB, asA, adA, asB, adB, h16, ssrc, sdst, N);
    }
}

// one block (1024 thr) per bucket: per-(dst,src-octile) hist + scan -> row/deg,
// LDS-slab scatter + per-key insertion sort by src id (octile is monotone in
// src, so rows come out fully src-sorted => csr is BIT-DETERMINISTIC regardless
// of atomic scatter order), then coalesced copy-out.
__global__ void bucket_build(const int* __restrict__ part, const int* __restrict__ bcursor,
                             int* __restrict__ row, int* __restrict__ deg,
                             int* __restrict__ csr, int n2, int N) {
    __shared__ int lhist[BG * 8];     // 1024 keys: dstLow*8 + srcOctile
    __shared__ int lrow[BG * 8];
    __shared__ int slab[CAP];         // 18 KB staging for deterministic sort
    int b = blockIdx.x, t = threadIdx.x;   // blockDim == 1024
    int start = b * CAP;
    int cnt = min(bcursor[b] - start, CAP);
    int cnt4 = cnt & ~3;
    int t1 = (N * 1) >> 3, t2 = (N * 2) >> 3, t3 = (N * 3) >> 3, t4 = (N * 4) >> 3;
    int t5 = (N * 5) >> 3, t6 = (N * 6) >> 3, t7 = (N * 7) >> 3;
    auto key = [&](int p) {
        int s = p >> 8;
        int o = (s >= t1) + (s >= t2) + (s >= t3) + (s >= t4)
              + (s >= t5) + (s >= t6) + (s >= t7);
        return ((p & 127) << 3) | o;
    };
    lhist[t] = 0;
    __syncthreads();
    for (int j = t * 4; j < cnt4; j += 4096) {
        int4 p = *(const int4*)(part + start + j);
        atomicAdd(&lhist[key(p.x)], 1);
        atomicAdd(&lhist[key(p.y)], 1);
        atomicAdd(&lhist[key(p.z)], 1);
        atomicAdd(&lhist[key(p.w)], 1);
    }
    for (int j = cnt4 + t; j < cnt; j += 1024) atomicAdd(&lhist[key(part[start + j])], 1);
    __syncthreads();
    int v = lhist[t];
    lrow[t] = v;
    __syncthreads();
    for (int off = 1; off < 1024; off <<= 1) {
        int a = (t >= off) ? lrow[t - off] : 0;
        __syncthreads();
        lrow[t] += a;
        __syncthreads();
    }
    // lrow = inclusive scan; key t's slab-relative segment = [lrow[t]-v, lrow[t])
    if (t < BG) {
        int g = b * BG + t;
        if (g < n2) {
            row[g] = start + lrow[8 * t] - lhist[8 * t];
            int d = 0;
#pragma unroll
            for (int i = 0; i < 8; i++) d += lhist[8 * t + i];
            deg[g] = d;
        }
    }
    __syncthreads();
    lhist[t] = lrow[t] - v;           // reuse as LDS-relative write cursor
    __syncthreads();
    for (int j = t * 4; j < cnt4; j += 4096) {
        int4 p = *(const int4*)(part + start + j);
        int pos;
        pos = atomicAdd(&lhist[key(p.x)], 1); slab[pos] = p.x >> 8;
        pos = atomicAdd(&lhist[key(p.y)], 1); slab[pos] = p.y >> 8;
        pos = atomicAdd(&lhist[key(p.z)], 1); slab[pos] = p.z >> 8;
        pos = atomicAdd(&lhist[key(p.w)], 1); slab[pos] = p.w >> 8;
    }
    for (int j = cnt4 + t; j < cnt; j += 1024) {
        int p = part[start + j];
        int pos = atomicAdd(&lhist[key(p)], 1);
        slab[pos] = p >> 8;
    }
    __syncthreads();
    // deterministic order: each thread insertion-sorts its key's segment
    // (Poisson(4) sizes, worst ~16 — cheap). Duplicate (dst,src) edges are
    // identical entries, so ties cannot introduce nondeterminism.
    {
        int ge = lrow[t], gs = ge - v;
        for (int i = gs + 1; i < ge; i++) {
            int x = slab[i], j2 = i - 1;
            while (j2 >= gs && slab[j2] > x) { slab[j2 + 1] = slab[j2]; j2--; }
            slab[j2 + 1] = x;
        }
    }
    __syncthreads();
    for (int j = t; j < cnt; j += 1024) csr[start + j] = slab[j];
}

// ---------------- layer-2 gemm with fused branch attention ----------------
__global__ void gemm2_fused(const float* __restrict__ hbig, const float* __restrict__ fha,
                            const float* __restrict__ WA, const float* __restrict__ WB,
                            const float* __restrict__ asA, const float* __restrict__ adA,
                            const float* __restrict__ asB, const float* __restrict__ adB,
                            __half* __restrict__ h16, float* __restrict__ ssrc,
                            float* __restrict__ sdst, int N) {
    __shared__ float xs[4][4 * ND];
    int half = blockIdx.x & 1;
    int blk = blockIdx.x >> 1;
    int wave = threadIdx.x >> 6;
    int lane = threadIdx.x & 63;
    const float* W  = half ? WB : WA;
    const float* av_ = half ? asB : asA;
    const float* dv_ = half ? adB : adA;
    int nodeBase = (blk * 4 + wave) * 4;
    float* xsw = xs[wave];

    if (nodeBase < N) {
        int nd = nodeBase + (lane >> 4);           // node this lane stages
        int col = (lane & 15) * 4;
        float4 vi = *(const float4*)&hbig[(size_t)nd * ND + col];
        float4 vp = *(const float4*)&hbig[((size_t)N + nd) * ND + col];
        float4 a0 = *(const float4*)&fha[col];
        float4 a1 = *(const float4*)&fha[ND + col];
        float p0 = vi.x * a0.x + vi.y * a0.y + vi.z * a0.z + vi.w * a0.w;
        float p1 = vp.x * a1.x + vp.y * a1.y + vp.z * a1.z + vp.w * a1.w;
#pragma unroll
        for (int m = 1; m <= 8; m <<= 1) {
            p0 += __shfl_xor(p0, m, 64);
            p1 += __shfl_xor(p1, m, 64);
        }
        float mx = fmaxf(p0, p1);
        float e0 = __expf(p0 - mx), e1 = __expf(p1 - mx);
        float inv = 1.f / (e0 + e1);
        float4 f;
        f.x = (e0 * vi.x + e1 * vp.x) * inv;
        f.y = (e0 * vi.y + e1 * vp.y) * inv;
        f.z = (e0 * vi.z + e1 * vp.z) * inv;
        f.w = (e0 * vi.w + e1 * vp.w) * inv;
        *(float4*)&xsw[lane * 4] = f;
    }
    __syncthreads();
    if (nodeBase >= N) return;

    float4 acc = {0.f, 0.f, 0.f, 0.f};
#pragma unroll
    for (int k = 0; k < ND; k++) {
        float wv = W[k * ND + lane];
        acc.x = fmaf(xsw[0 * ND + k], wv, acc.x);
        acc.y = fmaf(xsw[1 * ND + k], wv, acc.y);
        acc.z = fmaf(xsw[2 * ND + k], wv, acc.z);
        acc.w = fmaf(xsw[3 * ND + k], wv, acc.w);
    }
    float av = av_[lane], dv = dv_[lane];
    float s1x = wave_sum(acc.x * av), s2x = wave_sum(acc.x * dv);
    float s1y = wave_sum(acc.y * av), s2y = wave_sum(acc.y * dv);
    float s1z = wave_sum(acc.z * av), s2z = wave_sum(acc.z * dv);
    float s1w = wave_sum(acc.w * av), s2w = wave_sum(acc.w * dv);

    int g0 = half * N + nodeBase;
    h16[(size_t)(g0 + 0) * ND + lane] = __float2half(acc.x);
    h16[(size_t)(g0 + 1) * ND + lane] = __float2half(acc.y);
    h16[(size_t)(g0 + 2) * ND + lane] = __float2half(acc.z);
    h16[(size_t)(g0 + 3) * ND + lane] = __float2half(acc.w);
    if (lane == 0) {
        ssrc[g0] = s1x; sdst[g0] = s2x;
        ssrc[g0 + 1] = s1y; sdst[g0 + 1] = s2y;
        ssrc[g0 + 2] = s1z; sdst[g0 + 2] = s2z;
        ssrc[g0 + 3] = s1w; sdst[g0 + 3] = s2w;
    }
}

// ---------------- dual-graph aggregate: 4 nodes/wave, 16-edge chunks,
// 8 UNIFORM fully-unrolled steps per chunk (zero-padded weights), pre-shifted
// byte-offset broadcast, chunk-level csr/score prefetch ----------------
__global__ void aggregate_dual(const int* __restrict__ csr, const int* __restrict__ row,
                               const int* __restrict__ deg, const float* __restrict__ ssrc,
                               const float* __restrict__ sdst, const __half* __restrict__ h16,
                               const float* __restrict__ bA, const float* __restrict__ bB,
                               float* __restrict__ out, int N, int relu) {
    int half = blockIdx.x & 1;
    int wave = threadIdx.x >> 6;
    int lane = threadIdx.x & 63;
    int sub  = lane >> 4;             // which of the 4 nodes this lane serves
    int l16  = lane & 15;             // lane within the 16-lane group
    int slot = l16 >> 3;              // edge slot 0/1
    int fl8  = (l16 & 7) * 8;         // 8 halves owned by this lane
    int node = ((blockIdx.x >> 1) * 4 + wave) * 4 + sub;   // within half
    bool valid = node < N;
    int g = half * N + node;
    const float* bias = half ? bB : bA;
    const float* ss = ssrc + (size_t)half * N;       // per-half score table
    const __half* hh = h16 + (size_t)half * N * ND;  // per-half feature table
    const char* hp = (const char*)hh;                // byte base for row gathers
    int flb = fl8 * 2;                // byte offset of this lane's 16B within a row

    int start = valid ? row[g] : 0;
    int cnt   = valid ? deg[g] : 0;
    float sd  = valid ? sdst[g] : 0.f;
    float wself = valid ? __expf(lrelu(ss[node] + sd)) : 0.f;

    float acc[8] = {0.f, 0.f, 0.f, 0.f, 0.f, 0.f, 0.f, 0.f};
    float denomp = 0.f;
    int lbase = (sub << 4) + slot;    // shuffle source lane for step 0 of my slot

    // prologue: chunk 0 indices + weights (zero-padded past cnt)
    int c16 = min(16, cnt);
    int sj = (l16 < c16) ? csr[start + l16] : 0;
    float wj = (l16 < c16) ? __expf(lrelu(ss[sj] + sd)) : 0.f;

    for (int base = 0; base < cnt; base += 16) {
        // prefetch next chunk's indices + raw scores before the steps
        int nb2 = base + 16;
        int sn = 0; float vn = 0.f; int cn = cnt - nb2;
        if (nb2 < cnt) {
            sn = (l16 < cn) ? csr[start + nb2 + l16] : 0;
            vn = (l16 < cn) ? ss[sn] : 0.f;
        }
        denomp += wj;
        int sjb = sj << 7;            // row byte offset (ND*2 = 128); low 7 bits zero
        // 8 uniform steps: padded edges have w=0 (exact no-op) and gather row 0
        // (same-address broadcast, L1-hot). Full unroll => no pipeline-rotation
        // movs; compiler clusters the 16 bpermutes + 8 dwordx4 loads (8-deep MLP).
#pragma unroll
        for (int c = 0; c < 8; c++) {
            float w = __shfl(wj, lbase + 2 * c, 64);
            int   o = __shfl(sjb, lbase + 2 * c, 64);
            int4 r = *(const int4*)(hp + (o | flb));
            fma8(acc, w, r);
        }
        // finish next chunk's weights (exp after the latency-heavy phase)
        if (nb2 < cnt) {
            wj = (l16 < cn) ? __expf(lrelu(vn + sd)) : 0.f;
            sj = sn;
        }
    }

    // combine the 2 slots (single xor level)
#pragma unroll
    for (int i = 0; i < 8; i++) acc[i] += __shfl_xor(acc[i], 8, 64);
    // denom: sum over the 16-lane group
#pragma unroll
    for (int m = 1; m <= 8; m <<= 1) denomp += __shfl_xor(denomp, m, 64);
    float denom = denomp + wself;

    if (!valid || slot != 0) return;
    // self contribution + epilogue (8 lanes per group, 8 cols each)
    int4 rawS = *(const int4*)(hh + (size_t)node * ND + fl8);
    union { int4 i; __half h[8]; } us;
    us.i = rawS;
    float v[8];
#pragma unroll
    for (int i = 0; i < 8; i++)
        v[i] = (acc[i] + wself * __half2float(us.h[i])) / denom + bias[fl8 + i];
    if (relu) {
#pragma unroll
        for (int i = 0; i < 8; i++) v[i] = fmaxf(v[i], 0.f);
    }
    *(float4*)&out[(size_t)g * ND + fl8]     = make_float4(v[0], v[1], v[2], v[3]);
    *(float4*)&out[(size_t)g * ND + fl8 + 4] = make_float4(v[4], v[5], v[6], v[7]);
}

// branch attention + final 64->1 MLP
__global__ void branch_att_mlp(const float* __restrict__ hbig, const float* __restrict__ att,
                               const float* __restrict__ mlpw, const float* __restrict__ mlpb,
                               float* __restrict__ out, int n) {
    int gid = blockIdx.x * blockDim.x + threadIdx.x;
    int node = gid >> 6, lane = gid & 63;
    if (node >= n) return;
    float vi = hbig[(size_t)node * ND + lane];
    float vp = hbig[((size_t)n + node) * ND + lane];
    float s0 = wave_sum(att[lane] * vi);
    float s1 = wave_sum(att[ND + lane] * vp);
    float m = fmaxf(s0, s1);
    float a0 = __expf(s0 - m), a1 = __expf(s1 - m);
    float xj = (a0 * vi + a1 * vp) / (a0 + a1);
    float o = wave_sum(xj * mlpw[lane]);
    if (lane == 0) out[node] = o + mlpb[0];
}

extern "C" void kernel_launch(void* const* d_in, const int* in_sizes, int n_in,
                              void* d_out, int out_size, void* d_ws, size_t ws_size,
                              hipStream_t stream) {
    const int N = in_sizes[0] / ND;   // 50000
    const int E = in_sizes[2] / 2;    // 1600000

    const float* x_ind = (const float*)d_in[0];
    const float* x_pos = (const float*)d_in[1];
    const int*   e_ind = (const int*)d_in[2];
    const int*   e_pos = (const int*)d_in[3];
    const float* w1i = (const float*)d_in[4];
    const float* as1i = (const float*)d_in[5];
    const float* ad1i = (const float*)d_in[6];
    const float* b1i = (const float*)d_in[7];
    const float* w2i = (const float*)d_in[8];
    const float* as2i = (const float*)d_in[9];
    const float* ad2i = (const float*)d_in[10];
    const float* b2i = (const float*)d_in[11];
    const float* w1p = (const float*)d_in[12];
    const float* as1p = (const float*)d_in[13];
    const float* ad1p = (const float*)d_in[14];
    const float* b1p = (const float*)d_in[15];
    const float* w2p = (const float*)d_in[16];
    const float* as2p = (const float*)d_in[17];
    const float* ad2p = (const float*)d_in[18];
    const float* b2p = (const float*)d_in[19];
    const float* fha = (const float*)d_in[20];
    const float* attw = (const float*)d_in[21];
    const float* mlpw = (const float*)d_in[22];
    const float* mlpb = (const float*)d_in[23];

    char* ws = (char*)d_ws;
    size_t off = 0;
    auto alloc = [&](size_t elems) { void* p = ws + off; off += elems * 4; return p; };

    const int n2 = 2 * N;
    const int nb = (n2 + BG - 1) / BG;             // 782

    __half* h16 = (__half*)alloc((size_t)n2 * ND / 2);  // fp16 features both halves, 12.8 MB
    float* hbig = (float*)alloc((size_t)n2 * ND);       // layer outputs [I; P], 25.6 MB
    float* ssrc = (float*)alloc(n2);
    float* sdst = (float*)alloc(n2);
    int* deg    = (int*)alloc(n2);
    int* rowi   = (int*)alloc(n2);
    int* csr    = (int*)alloc((size_t)nb * CAP);        // 14.4 MB slabs
    int* bcursor= (int*)alloc(MAXB);
    // part[nb*CAP] ints alias hbig (25.6 MB >= 14.4 MB) — consumed by
    // bucket_build before the first aggregate_dual writes hbig
    int* part   = (int*)hbig;

    const int partBlocks  = (2 * E + PCH - 1) / PCH;        // 196
    const int gemm1Blocks = 2 * ((N + 63) / 64);            // 1564 (64 nodes/block/half)
    const int gemm2Blocks = 2 * ((N + 15) / 16);            // 6250
    const int aggBlocks   = 2 * ((N + 15) / 16);            // 6250
    const int nodeBlocks  = (N + 3) / 4;                    // 12500

    // ---- CSR build overlapped with layer-1 gemm (independent work) ----
    init_cursor<<<1, 1024, 0, stream>>>(bcursor, nb);
    part_gemm<<<partBlocks + gemm1Blocks, 1024, 0, stream>>>(
        e_ind, e_pos, bcursor, part,
        x_ind, x_pos, w1i, w1p, as1i, ad1i, as1p, ad1p,
        h16, ssrc, sdst, N, E, nb, partBlocks);
    bucket_build<<<nb, 1024, 0, stream>>>(part, bcursor, rowi, deg, csr, n2, N);

    // ---- layer 1 aggregate ----
    aggregate_dual<<<aggBlocks, 256, 0, stream>>>(csr, rowi, deg, ssrc, sdst, h16,
                                                  b1i, b1p, hbig, N, 1);

    // ---- layer 2 (branch attention fused into the gemm) ----
    gemm2_fused<<<gemm2Blocks, 256, 0, stream>>>(hbig, fha, w2i, w2p,
                                                 as2i, ad2i, as2p, ad2p,
                                                 h16, ssrc, sdst, N);
    aggregate_dual<<<aggBlocks, 256, 0, stream>>>(csr, rowi, deg, ssrc, sdst, h16,
                                                  b2i, b2p, hbig, N, 0);
    branch_att_mlp<<<nodeBlocks, 256, 0, stream>>>(hbig, attw, mlpw, mlpb,
                                                   (float*)d_out, N);
}

// Round 4
// 333.911 us; speedup vs baseline: 1.0320x; 1.0119x over previous
//
#include <hip/hip_runtime.h>
#include <hip/hip_fp16.h>

#define ND 64
#define BG 128        // dst ids per bucket
#define MAXB 1024     // max buckets (LDS sizing); nb = ceil(2N/BG) = 782
#define PCH 16384     // edges per partition chunk: 196 part-blocks
#define CAP 4608      // per-bucket slab capacity; lambda=4096, sigma~64 -> 8-sigma margin

__device__ __forceinline__ float lrelu(float x) { return x > 0.f ? x : 0.2f * x; }

__device__ __forceinline__ float wave_sum(float v) {
#pragma unroll
    for (int m = 32; m > 0; m >>= 1) v += __shfl_xor(v, m, 64);
    return v;
}

// 8 fp16 x fp32 fused into 8 fp32 accumulators (v_fma_mix_f32 form)
__device__ __forceinline__ void fma8(float* acc, float w, int4 raw) {
    union { int4 i; __half h[8]; } u;
    u.i = raw;
#pragma unroll
    for (int i = 0; i < 8; i++) acc[i] = fmaf(w, __half2float(u.h[i]), acc[i]);
}

// ---------------- bucketed CSR build (fixed-capacity slabs) ----------------

__global__ void init_cursor(int* __restrict__ bcursor, int nb) {
    int t = threadIdx.x;
    if (t < nb) bcursor[t] = t * CAP;
}

__device__ void partition_body(int* hist, int* lcur,
                               const int* __restrict__ eI, const int* __restrict__ eP,
                               int* __restrict__ bcursor, int* __restrict__ part,
                               int N, int E, int nb) {
    int t = threadIdx.x;
    int total = 2 * E;
    int chunkBase = blockIdx.x * PCH;
    int cnt = min(PCH, total - chunkBase);
    if (t < nb) hist[t] = 0;
    __syncthreads();

    if (cnt == PCH) {
        int pk[16];
        unsigned bkp[8];
#pragma unroll
        for (int it = 0; it < 4; it++) {
            int i = t * 4 + it * 4096;
            int e = chunkBase + i;
            int sv[4], dv[4];
            if (e + 3 < E) {
                int4 a = *(const int4*)(eI + e);
                int4 b = *(const int4*)(eI + E + e);
                sv[0] = a.x; sv[1] = a.y; sv[2] = a.z; sv[3] = a.w;
                dv[0] = b.x; dv[1] = b.y; dv[2] = b.z; dv[3] = b.w;
            } else if (e >= E) {
                int4 a = *(const int4*)(eP + (e - E));
                int4 b = *(const int4*)(eP + E + (e - E));
                sv[0] = a.x; sv[1] = a.y; sv[2] = a.z; sv[3] = a.w;
                dv[0] = b.x + N; dv[1] = b.y + N; dv[2] = b.z + N; dv[3] = b.w + N;
            } else {
#pragma unroll
                for (int k = 0; k < 4; k++) {
                    int ee = e + k;
                    if (ee < E) { sv[k] = eI[ee]; dv[k] = eI[E + ee]; }
                    else        { sv[k] = eP[ee - E]; dv[k] = N + eP[E + ee - E]; }
                }
            }
#pragma unroll
            for (int k = 0; k < 4; k++) {
                int j = it * 4 + k;
                int bk = dv[k] >> 7;
                pk[j] = (sv[k] << 8) | (dv[k] & 255);
                atomicAdd(&hist[bk], 1);
                if ((j & 1) == 0) bkp[j >> 1] = (unsigned)bk;
                else bkp[j >> 1] |= (unsigned)bk << 16;
            }
        }
        __syncthreads();
        if (t < nb) lcur[t] = hist[t] ? atomicAdd(&bcursor[t], hist[t]) : 0;
        __syncthreads();
#pragma unroll
        for (int j = 0; j < 16; j++) {
            int bk = (bkp[j >> 1] >> ((j & 1) * 16)) & 0xffff;
            int pos = atomicAdd(&lcur[bk], 1);
            part[pos] = pk[j];
        }
        return;
    }

    // slow path (tail chunk only)
    int cnt4 = cnt & ~3;
    for (int i = t * 4; i < cnt4; i += 4096) {
        int e = chunkBase + i;
        int4 d; int base;
        if (e + 3 < E)   { d = *(const int4*)(eI + E + e); base = 0; }
        else if (e >= E) { d = *(const int4*)(eP + E + (e - E)); base = N; }
        else {
            int tmp[4];
#pragma unroll
            for (int k = 0; k < 4; k++) {
                int ee = e + k;
                tmp[k] = (ee < E) ? eI[E + ee] : N + eP[E + ee - E];
            }
            d = make_int4(tmp[0], tmp[1], tmp[2], tmp[3]); base = 0;
        }
        atomicAdd(&hist[(base + d.x) >> 7], 1);
        atomicAdd(&hist[(base + d.y) >> 7], 1);
        atomicAdd(&hist[(base + d.z) >> 7], 1);
        atomicAdd(&hist[(base + d.w) >> 7], 1);
    }
    for (int i = cnt4 + t; i < cnt; i += 1024) {
        int e = chunkBase + i;
        int idx = (e < E) ? eI[E + e] : N + eP[E + (e - E)];
        atomicAdd(&hist[idx >> 7], 1);
    }
    __syncthreads();
    if (t < nb) lcur[t] = hist[t] ? atomicAdd(&bcursor[t], hist[t]) : 0;
    __syncthreads();
    for (int i = t; i < cnt; i += 1024) {
        int e = chunkBase + i;
        int s, idx;
        if (e < E) { s = eI[e]; idx = eI[E + e]; }
        else       { s = eP[e - E]; idx = N + eP[E + (e - E)]; }
        int pos = atomicAdd(&lcur[idx >> 7], 1);
        part[pos] = (s << 8) | (idx & 255);
    }
}

// ---- gemm body: h(fp16) = x @ W + score dots; 16 waves/block, 4 nodes/wave ----
__device__ void gemm_body(float* xsAll, int gb,
                          const float* __restrict__ xA, const float* __restrict__ xB,
                          const float* __restrict__ WA, const float* __restrict__ WB,
                          const float* __restrict__ asA, const float* __restrict__ adA,
                          const float* __restrict__ asB, const float* __restrict__ adB,
                          __half* __restrict__ h16, float* __restrict__ ssrc,
                          float* __restrict__ sdst, int N) {
    int half = gb & 1;
    int blk = gb >> 1;
    int wave = threadIdx.x >> 6;
    int lane = threadIdx.x & 63;
    const float* x  = half ? xB : xA;
    const float* W  = half ? WB : WA;
    const float* av_ = half ? asB : asA;
    const float* dv_ = half ? adB : adA;
    int nodeBase = (blk * 16 + wave) * 4;      // within half
    float* xs = xsAll + wave * (4 * ND);

    if (nodeBase + 3 < N) {
        *(float4*)&xs[lane * 4] = *(const float4*)&x[(size_t)nodeBase * ND + lane * 4];
    } else if (nodeBase < N) {
#pragma unroll
        for (int i = 0; i < 4; i++) {
            int gi = nodeBase * ND + lane * 4 + i;
            xs[lane * 4 + i] = (gi < N * ND) ? x[gi] : 0.f;
        }
    }
    __syncthreads();
    if (nodeBase >= N) return;

    float4 acc = {0.f, 0.f, 0.f, 0.f};
#pragma unroll
    for (int k = 0; k < ND; k++) {
        float wv = W[k * ND + lane];
        acc.x = fmaf(xs[0 * ND + k], wv, acc.x);
        acc.y = fmaf(xs[1 * ND + k], wv, acc.y);
        acc.z = fmaf(xs[2 * ND + k], wv, acc.z);
        acc.w = fmaf(xs[3 * ND + k], wv, acc.w);
    }
    float av = av_[lane], dv = dv_[lane];
    float s1x = wave_sum(acc.x * av), s2x = wave_sum(acc.x * dv);
    float s1y = wave_sum(acc.y * av), s2y = wave_sum(acc.y * dv);
    float s1z = wave_sum(acc.z * av), s2z = wave_sum(acc.z * dv);
    float s1w = wave_sum(acc.w * av), s2w = wave_sum(acc.w * dv);

    int g0 = half * N + nodeBase;
    h16[(size_t)(g0 + 0) * ND + lane] = __float2half(acc.x);
    if (nodeBase + 1 < N) h16[(size_t)(g0 + 1) * ND + lane] = __float2half(acc.y);
    if (nodeBase + 2 < N) h16[(size_t)(g0 + 2) * ND + lane] = __float2half(acc.z);
    if (nodeBase + 3 < N) h16[(size_t)(g0 + 3) * ND + lane] = __float2half(acc.w);
    if (lane == 0) {
        ssrc[g0] = s1x; sdst[g0] = s2x;
        if (nodeBase + 1 < N) { ssrc[g0 + 1] = s1y; sdst[g0 + 1] = s2y; }
        if (nodeBase + 2 < N) { ssrc[g0 + 2] = s1z; sdst[g0 + 2] = s2z; }
        if (nodeBase + 3 < N) { ssrc[g0 + 3] = s1w; sdst[g0 + 3] = s2w; }
    }
}

// ---- fused: partition (blocks < partBlocks) | layer-1 gemm (the rest) ----
__global__ void __launch_bounds__(1024) part_gemm(
        const int* __restrict__ eI, const int* __restrict__ eP,
        int* __restrict__ bcursor, int* __restrict__ part,
        const float* __restrict__ xA, const float* __restrict__ xB,
        const float* __restrict__ WA, const float* __restrict__ WB,
        const float* __restrict__ asA, const float* __restrict__ adA,
        const float* __restrict__ asB, const float* __restrict__ adB,
        __half* __restrict__ h16, float* __restrict__ ssrc, float* __restrict__ sdst,
        int N, int E, int nb, int partBlocks) {
    __shared__ int smem[16 * 4 * ND];   // 16 KB
    if (blockIdx.x < partBlocks) {
        partition_body(smem, smem + MAXB, eI, eP, bcursor, part, N, E, nb);
    } else {
        gemm_body((float*)smem, blockIdx.x - partBlocks,
                  xA, xB, WA, WB, asA, adA, asB, adB, h16, ssrc, sdst, N);
    }
}

// one block (1024 thr) per bucket: hist + scan -> row/deg, LDS scatter +
// per-key insertion sort by src (deterministic csr), coalesced copy-out.
__global__ void bucket_build(const int* __restrict__ part, const int* __restrict__ bcursor,
                             int* __restrict__ row, int* __restrict__ deg,
                             int* __restrict__ csr, int n2, int N) {
    __shared__ int lhist[BG * 8];
    __shared__ int lrow[BG * 8];
    __shared__ int slab[CAP];
    int b = blockIdx.x, t = threadIdx.x;
    int start = b * CAP;
    int cnt = min(bcursor[b] - start, CAP);
    int cnt4 = cnt & ~3;
    int t1 = (N * 1) >> 3, t2 = (N * 2) >> 3, t3 = (N * 3) >> 3, t4 = (N * 4) >> 3;
    int t5 = (N * 5) >> 3, t6 = (N * 6) >> 3, t7 = (N * 7) >> 3;
    auto key = [&](int p) {
        int s = p >> 8;
        int o = (s >= t1) + (s >= t2) + (s >= t3) + (s >= t4)
              + (s >= t5) + (s >= t6) + (s >= t7);
        return ((p & 127) << 3) | o;
    };
    lhist[t] = 0;
    __syncthreads();
    for (int j = t * 4; j < cnt4; j += 4096) {
        int4 p = *(const int4*)(part + start + j);
        atomicAdd(&lhist[key(p.x)], 1);
        atomicAdd(&lhist[key(p.y)], 1);
        atomicAdd(&lhist[key(p.z)], 1);
        atomicAdd(&lhist[key(p.w)], 1);
    }
    for (int j = cnt4 + t; j < cnt; j += 1024) atomicAdd(&lhist[key(part[start + j])], 1);
    __syncthreads();
    int v = lhist[t];
    lrow[t] = v;
    __syncthreads();
    for (int off = 1; off < 1024; off <<= 1) {
        int a = (t >= off) ? lrow[t - off] : 0;
        __syncthreads();
        lrow[t] += a;
        __syncthreads();
    }
    if (t < BG) {
        int g = b * BG + t;
        if (g < n2) {
            row[g] = start + lrow[8 * t] - lhist[8 * t];
            int d = 0;
#pragma unroll
            for (int i = 0; i < 8; i++) d += lhist[8 * t + i];
            deg[g] = d;
        }
    }
    __syncthreads();
    lhist[t] = lrow[t] - v;
    __syncthreads();
    for (int j = t * 4; j < cnt4; j += 4096) {
        int4 p = *(const int4*)(part + start + j);
        int pos;
        pos = atomicAdd(&lhist[key(p.x)], 1); slab[pos] = p.x >> 8;
        pos = atomicAdd(&lhist[key(p.y)], 1); slab[pos] = p.y >> 8;
        pos = atomicAdd(&lhist[key(p.z)], 1); slab[pos] = p.z >> 8;
        pos = atomicAdd(&lhist[key(p.w)], 1); slab[pos] = p.w >> 8;
    }
    for (int j = cnt4 + t; j < cnt; j += 1024) {
        int p = part[start + j];
        int pos = atomicAdd(&lhist[key(p)], 1);
        slab[pos] = p >> 8;
    }
    __syncthreads();
    {
        int ge = lrow[t], gs = ge - v;
        for (int i = gs + 1; i < ge; i++) {
            int x = slab[i], j2 = i - 1;
            while (j2 >= gs && slab[j2] > x) { slab[j2 + 1] = slab[j2]; j2--; }
            slab[j2 + 1] = x;
        }
    }
    __syncthreads();
    for (int j = t; j < cnt; j += 1024) csr[start + j] = slab[j];
}

// ================= fused aggregates =================
// Block = 256 thr = 4 waves; wave w: half = w>>1, nodes blk*8 + (w&1)*4 + sub.
// Each wave's 4 groups of 16 lanes run the r1-proven gather (16-edge chunks,
// depth-3 pipeline). Epilogues combine both halves of the same node via LDS.

// GATHER macro body: fills acc[8]/denomp/wself for (node,half); r1 verbatim.
__device__ __forceinline__ void gather_body(
        const int* __restrict__ csr, int start, int cnt, float sd,
        const float* __restrict__ ss, const __half* __restrict__ hh,
        int l16, int slot, int fl8, int waveBase,
        float* acc, float& denomp) {
    int c16 = min(16, cnt);
    int sj = (l16 < c16) ? csr[start + l16] : 0;
    float wj = (l16 < c16) ? __expf(lrelu(ss[sj] + sd)) : 0.f;

    for (int base = 0; base < cnt; base += 16) {
        int nb2 = base + 16;
        int sjn = 0; float svn = 0.f; int c16n = cnt - nb2;
        if (nb2 < cnt) {
            sjn = (l16 < c16n) ? csr[start + nb2 + l16] : 0;
            svn = (l16 < c16n) ? ss[sjn] : 0.f;
        }
        denomp += wj;
        int nq = (min(16, cnt - base) + 1) >> 1;
        float w0 = __shfl(wj, waveBase + slot, 64);
        int s0 = __shfl(sj, waveBase + slot, 64);
        int4 r0 = *(const int4*)(hh + (size_t)s0 * ND + fl8);
        if (nq > 1) {
            float w1 = __shfl(wj, waveBase + 2 + slot, 64);
            int s1 = __shfl(sj, waveBase + 2 + slot, 64);
            int4 r1 = *(const int4*)(hh + (size_t)s1 * ND + fl8);
            for (int c = 2; c < nq; c++) {
                float w2 = __shfl(wj, waveBase + c * 2 + slot, 64);
                int s2 = __shfl(sj, waveBase + c * 2 + slot, 64);
                int4 r2 = *(const int4*)(hh + (size_t)s2 * ND + fl8);
                fma8(acc, w0, r0);
                w0 = w1; r0 = r1;
                w1 = w2; r1 = r2;
            }
            fma8(acc, w0, r0);
            fma8(acc, w1, r1);
        } else {
            fma8(acc, w0, r0);
        }
        if (nb2 < cnt) {
            wj = (l16 < c16n) ? __expf(lrelu(svn + sd)) : 0.f;
            sj = sjn;
        }
    }
}

// ---- layer-1 aggregate + first-hop attention + layer-2 gemm (fused) ----
__global__ void agg1_gemm2(
        const int* __restrict__ csr, const int* __restrict__ row,
        const int* __restrict__ deg, const float* __restrict__ ss1,
        const float* __restrict__ sd1, const __half* __restrict__ h16a,
        const float* __restrict__ b1A, const float* __restrict__ b1B,
        const float* __restrict__ fha,
        const float* __restrict__ W2A, const float* __restrict__ W2B,
        const float* __restrict__ as2A, const float* __restrict__ ad2A,
        const float* __restrict__ as2B, const float* __restrict__ ad2B,
        __half* __restrict__ h16b, float* __restrict__ ssrc2,
        float* __restrict__ sdst2, int N) {
    __shared__ float lds_h[2][8][ND];   // relu'd layer-1 outputs, both halves
    __shared__ float lds_f[8][ND];      // fused features
    int wave = threadIdx.x >> 6, lane = threadIdx.x & 63;
    int half = wave >> 1;
    int sub = lane >> 4, l16 = lane & 15, slot = l16 >> 3, fl8 = (l16 & 7) * 8;
    int nodeIdx = (wave & 1) * 4 + sub;
    int node = blockIdx.x * 8 + nodeIdx;
    bool valid = node < N;
    int g = half * N + node;
    const float* bias = half ? b1B : b1A;
    const float* ss = ss1 + (size_t)half * N;
    const __half* hh = h16a + (size_t)half * N * ND;

    int start = valid ? row[g] : 0;
    int cnt   = valid ? deg[g] : 0;
    float sd  = valid ? sd1[g] : 0.f;
    float wself = valid ? __expf(lrelu(ss[node] + sd)) : 0.f;

    float acc[8] = {0.f, 0.f, 0.f, 0.f, 0.f, 0.f, 0.f, 0.f};
    float denomp = 0.f;
    gather_body(csr, start, cnt, sd, ss, hh, l16, slot, fl8, sub << 4, acc, denomp);

#pragma unroll
    for (int i = 0; i < 8; i++) acc[i] += __shfl_xor(acc[i], 8, 64);
#pragma unroll
    for (int m = 1; m <= 8; m <<= 1) denomp += __shfl_xor(denomp, m, 64);
    float denom = denomp + wself;

    if (slot == 0) {
        if (valid) {
            int4 rawS = *(const int4*)(hh + (size_t)node * ND + fl8);
            union { int4 i; __half h[8]; } us;
            us.i = rawS;
#pragma unroll
            for (int i = 0; i < 8; i++)
                lds_h[half][nodeIdx][fl8 + i] =
                    fmaxf((acc[i] + wself * __half2float(us.h[i])) / denom + bias[fl8 + i], 0.f);
        } else {
#pragma unroll
            for (int i = 0; i < 8; i++) lds_h[half][nodeIdx][fl8 + i] = 0.f;
        }
    }
    __syncthreads();

    // first-hop branch attention: each wave combines 2 nodes (all lanes)
#pragma unroll
    for (int r = 0; r < 2; r++) {
        int n = wave * 2 + r;
        float vi = lds_h[0][n][lane], vp = lds_h[1][n][lane];
        float p0 = wave_sum(fha[lane] * vi);
        float p1 = wave_sum(fha[ND + lane] * vp);
        float mx = fmaxf(p0, p1);
        float e0 = __expf(p0 - mx), e1 = __expf(p1 - mx);
        float inv = 1.f / (e0 + e1);
        lds_f[n][lane] = (e0 * vi + e1 * vp) * inv;
    }
    __syncthreads();

    // layer-2 gemm: wave computes 4 nodes x its half; h2 = fused @ W2 + scores
    {
        const float* W  = half ? W2B : W2A;
        const float* av_ = half ? as2B : as2A;
        const float* dv_ = half ? ad2B : ad2A;
        int nb0 = (wave & 1) * 4;
        float4 a2 = {0.f, 0.f, 0.f, 0.f};
#pragma unroll
        for (int k = 0; k < ND; k++) {
            float wv = W[k * ND + lane];
            a2.x = fmaf(lds_f[nb0 + 0][k], wv, a2.x);
            a2.y = fmaf(lds_f[nb0 + 1][k], wv, a2.y);
            a2.z = fmaf(lds_f[nb0 + 2][k], wv, a2.z);
            a2.w = fmaf(lds_f[nb0 + 3][k], wv, a2.w);
        }
        float av = av_[lane], dv = dv_[lane];
        float s1x = wave_sum(a2.x * av), s2x = wave_sum(a2.x * dv);
        float s1y = wave_sum(a2.y * av), s2y = wave_sum(a2.y * dv);
        float s1z = wave_sum(a2.z * av), s2z = wave_sum(a2.z * dv);
        float s1w = wave_sum(a2.w * av), s2w = wave_sum(a2.w * dv);

        int n0 = blockIdx.x * 8 + nb0;
        int g0 = half * N + n0;
        if (n0 + 0 < N) h16b[(size_t)(g0 + 0) * ND + lane] = __float2half(a2.x);
        if (n0 + 1 < N) h16b[(size_t)(g0 + 1) * ND + lane] = __float2half(a2.y);
        if (n0 + 2 < N) h16b[(size_t)(g0 + 2) * ND + lane] = __float2half(a2.z);
        if (n0 + 3 < N) h16b[(size_t)(g0 + 3) * ND + lane] = __float2half(a2.w);
        if (lane == 0) {
            if (n0 + 0 < N) { ssrc2[g0 + 0] = s1x; sdst2[g0 + 0] = s2x; }
            if (n0 + 1 < N) { ssrc2[g0 + 1] = s1y; sdst2[g0 + 1] = s2y; }
            if (n0 + 2 < N) { ssrc2[g0 + 2] = s1z; sdst2[g0 + 2] = s2z; }
            if (n0 + 3 < N) { ssrc2[g0 + 3] = s1w; sdst2[g0 + 3] = s2w; }
        }
    }
}

// ---- layer-2 aggregate + branch attention + final 64->1 MLP (fused) ----
__global__ void agg2_mlp(
        const int* __restrict__ csr, const int* __restrict__ row,
        const int* __restrict__ deg, const float* __restrict__ ss2,
        const float* __restrict__ sd2, const __half* __restrict__ h16b,
        const float* __restrict__ b2A, const float* __restrict__ b2B,
        const float* __restrict__ attw, const float* __restrict__ mlpw,
        const float* __restrict__ mlpb,
        float* __restrict__ out, int N) {
    __shared__ float lds_h[2][8][ND];
    int wave = threadIdx.x >> 6, lane = threadIdx.x & 63;
    int half = wave >> 1;
    int sub = lane >> 4, l16 = lane & 15, slot = l16 >> 3, fl8 = (l16 & 7) * 8;
    int nodeIdx = (wave & 1) * 4 + sub;
    int node = blockIdx.x * 8 + nodeIdx;
    bool valid = node < N;
    int g = half * N + node;
    const float* bias = half ? b2B : b2A;
    const float* ss = ss2 + (size_t)half * N;
    const __half* hh = h16b + (size_t)half * N * ND;

    int start = valid ? row[g] : 0;
    int cnt   = valid ? deg[g] : 0;
    float sd  = valid ? sd2[g] : 0.f;
    float wself = valid ? __expf(lrelu(ss[node] + sd)) : 0.f;

    float acc[8] = {0.f, 0.f, 0.f, 0.f, 0.f, 0.f, 0.f, 0.f};
    float denomp = 0.f;
    gather_body(csr, start, cnt, sd, ss, hh, l16, slot, fl8, sub << 4, acc, denomp);

#pragma unroll
    for (int i = 0; i < 8; i++) acc[i] += __shfl_xor(acc[i], 8, 64);
#pragma unroll
    for (int m = 1; m <= 8; m <<= 1) denomp += __shfl_xor(denomp, m, 64);
    float denom = denomp + wself;

    if (slot == 0) {
        if (valid) {
            int4 rawS = *(const int4*)(hh + (size_t)node * ND + fl8);
            union { int4 i; __half h[8]; } us;
            us.i = rawS;
#pragma unroll
            for (int i = 0; i < 8; i++)
                lds_h[half][nodeIdx][fl8 + i] =
                    (acc[i] + wself * __half2float(us.h[i])) / denom + bias[fl8 + i];
        } else {
#pragma unroll
            for (int i = 0; i < 8; i++) lds_h[half][nodeIdx][fl8 + i] = 0.f;
        }
    }
    __syncthreads();

    // branch attention + MLP: each wave finishes 2 nodes
#pragma unroll
    for (int r = 0; r < 2; r++) {
        int n = wave * 2 + r;
        int gn = blockIdx.x * 8 + n;
        float vi = lds_h[0][n][lane], vp = lds_h[1][n][lane];
        float s0 = wave_sum(attw[lane] * vi);
        float s1 = wave_sum(attw[ND + lane] * vp);
        float m = fmaxf(s0, s1);
        float a0 = __expf(s0 - m), a1 = __expf(s1 - m);
        float xj = (a0 * vi + a1 * vp) / (a0 + a1);
        float o = wave_sum(xj * mlpw[lane]);
        if (lane == 0 && gn < N) out[gn] = o + mlpb[0];
    }
}

extern "C" void kernel_launch(void* const* d_in, const int* in_sizes, int n_in,
                              void* d_out, int out_size, void* d_ws, size_t ws_size,
                              hipStream_t stream) {
    const int N = in_sizes[0] / ND;   // 50000
    const int E = in_sizes[2] / 2;    // 1600000

    const float* x_ind = (const float*)d_in[0];
    const float* x_pos = (const float*)d_in[1];
    const int*   e_ind = (const int*)d_in[2];
    const int*   e_pos = (const int*)d_in[3];
    const float* w1i = (const float*)d_in[4];
    const float* as1i = (const float*)d_in[5];
    const float* ad1i = (const float*)d_in[6];
    const float* b1i = (const float*)d_in[7];
    const float* w2i = (const float*)d_in[8];
    const float* as2i = (const float*)d_in[9];
    const float* ad2i = (const float*)d_in[10];
    const float* b2i = (const float*)d_in[11];
    const float* w1p = (const float*)d_in[12];
    const float* as1p = (const float*)d_in[13];
    const float* ad1p = (const float*)d_in[14];
    const float* b1p = (const float*)d_in[15];
    const float* w2p = (const float*)d_in[16];
    const float* as2p = (const float*)d_in[17];
    const float* ad2p = (const float*)d_in[18];
    const float* b2p = (const float*)d_in[19];
    const float* fha = (const float*)d_in[20];
    const float* attw = (const float*)d_in[21];
    const float* mlpw = (const float*)d_in[22];
    const float* mlpb = (const float*)d_in[23];

    char* ws = (char*)d_ws;
    size_t off = 0;
    auto alloc = [&](size_t elems) { void* p = ws + off; off += elems * 4; return p; };

    const int n2 = 2 * N;
    const int nb = (n2 + BG - 1) / BG;             // 782

    __half* h16a = (__half*)alloc((size_t)n2 * ND / 2);  // layer-1 fp16 features, 12.8 MB
    float* ssrc1 = (float*)alloc(n2);
    float* sdst1 = (float*)alloc(n2);
    float* ssrc2 = (float*)alloc(n2);
    float* sdst2 = (float*)alloc(n2);
    int* deg    = (int*)alloc(n2);
    int* rowi   = (int*)alloc(n2);
    int* csr    = (int*)alloc((size_t)nb * CAP);        // 14.4 MB slabs
    int* bcursor= (int*)alloc(MAXB);
    int* part   = (int*)alloc((size_t)nb * CAP);        // 14.4 MB
    // h16b aliases part (12.8 <= 14.4 MB): part is consumed by bucket_build
    // before agg1_gemm2 writes h16b.
    __half* h16b = (__half*)part;

    const int partBlocks  = (2 * E + PCH - 1) / PCH;        // 196
    const int gemm1Blocks = 2 * ((N + 63) / 64);            // 1564
    const int fusedBlocks = (N + 7) / 8;                    // 6250 (8 nodes x 2 halves)

    // ---- CSR build overlapped with layer-1 gemm (independent work) ----
    init_cursor<<<1, 1024, 0, stream>>>(bcursor, nb);
    part_gemm<<<partBlocks + gemm1Blocks, 1024, 0, stream>>>(
        e_ind, e_pos, bcursor, part,
        x_ind, x_pos, w1i, w1p, as1i, ad1i, as1p, ad1p,
        h16a, ssrc1, sdst1, N, E, nb, partBlocks);
    bucket_build<<<nb, 1024, 0, stream>>>(part, bcursor, rowi, deg, csr, n2, N);

    // ---- layer-1 aggregate + first-hop attention + layer-2 gemm ----
    agg1_gemm2<<<fusedBlocks, 256, 0, stream>>>(
        csr, rowi, deg, ssrc1, sdst1, h16a, b1i, b1p, fha,
        w2i, w2p, as2i, ad2i, as2p, ad2p, h16b, ssrc2, sdst2, N);

    // ---- layer-2 aggregate + branch attention + final MLP ----
    agg2_mlp<<<fusedBlocks, 256, 0, stream>>>(
        csr, rowi, deg, ssrc2, sdst2, h16b, b2i, b2p,
        attw, mlpw, mlpb, (float*)d_out, N);
}